// Round 15
// baseline (171.948 us; speedup 1.0000x reference)
//
#include <hip/hip_runtime.h>
#include <stdint.h>

#define N_NODES 50000
#define N_EDGES 800000
#define D 128
#define DOUT 64

#define CSR_BLK 256
#define CSR_NBLK ((N_NODES + CSR_BLK - 1) / CSR_BLK)  // 196

#define BSH 7                                  // rows per bucket = 128
#define NBUCK ((N_NODES + 127) >> BSH)         // 391
#define EPB 4096                               // edges per bucket_scatter block
#define SC_NBLK ((N_EDGES + EPB - 1) / EPB)    // 196

typedef short bf16x8 __attribute__((ext_vector_type(8)));
typedef float f32x4 __attribute__((ext_vector_type(4)));

__host__ __device__ inline uint32_t rotl32(uint32_t v, int d) {
    return (v << d) | (v >> (32 - d));
}

// JAX threefry2x32 (20 rounds), matches jax/_src/prng.py
__host__ __device__ inline void threefry2x32(uint32_t k0, uint32_t k1,
                                             uint32_t x0, uint32_t x1,
                                             uint32_t& o0, uint32_t& o1) {
    uint32_t ks2 = 0x1BD11BDAu ^ k0 ^ k1;
    x0 += k0; x1 += k1;
#define TFR(d) { x0 += x1; x1 = rotl32(x1, d); x1 ^= x0; }
    TFR(13) TFR(15) TFR(26) TFR(6)
    x0 += k1;  x1 += ks2 + 1u;
    TFR(17) TFR(29) TFR(16) TFR(24)
    x0 += ks2; x1 += k0 + 2u;
    TFR(13) TFR(15) TFR(26) TFR(6)
    x0 += k0;  x1 += k1 + 3u;
    TFR(17) TFR(29) TFR(16) TFR(24)
    x0 += k1;  x1 += ks2 + 4u;
    TFR(13) TFR(15) TFR(26) TFR(6)
    x0 += ks2; x1 += k0 + 5u;
#undef TFR
    o0 = x0; o1 = x1;
}

__device__ inline bool keep_mask(uint32_t k0, uint32_t k1, uint32_t j) {
    uint32_t b0, b1;
    threefry2x32(k0, k1, 0u, j, b0, b1);
    uint32_t bits = b0 ^ b1;
    float u = __uint_as_float((bits >> 9) | 0x3f800000u) - 1.0f;
    return u < 0.5f;
}

__device__ inline uint32_t f2bf(float f) {
    uint32_t u = __float_as_uint(f);
    return (u + 0x7fffu + ((u >> 16) & 1u)) >> 16;
}
__device__ inline float bf2f_lo(uint32_t u) { return __uint_as_float(u << 16); }
__device__ inline float bf2f_hi(uint32_t u) { return __uint_as_float(u & 0xffff0000u); }

__device__ inline void fma8(float* a, uint4 u, float w) {
    a[0] = fmaf(w, bf2f_lo(u.x), a[0]);
    a[1] = fmaf(w, bf2f_hi(u.x), a[1]);
    a[2] = fmaf(w, bf2f_lo(u.y), a[2]);
    a[3] = fmaf(w, bf2f_hi(u.y), a[3]);
    a[4] = fmaf(w, bf2f_lo(u.z), a[4]);
    a[5] = fmaf(w, bf2f_hi(u.z), a[5]);
    a[6] = fmaf(w, bf2f_lo(u.w), a[6]);
    a[7] = fmaf(w, bf2f_hi(u.w), a[7]);
}

// ---------------- fused0: dropout(X)->bf16 | weight transpose | degree hist ----------------
__global__ void fused0_kernel(const float* __restrict__ X, ushort* __restrict__ Xb,
                              const float* __restrict__ W1, const float* __restrict__ W2,
                              ushort* __restrict__ W1T, ushort* __restrict__ W2T,
                              const int* __restrict__ rows, int* __restrict__ deg,
                              uint32_t k0, uint32_t k1) {
    int t = blockIdx.x * blockDim.x + threadIdx.x;
    if (t < N_NODES * D / 8) {
        float4 v0 = ((const float4*)X)[t * 2];
        float4 v1 = ((const float4*)X)[t * 2 + 1];
        uint32_t j = (uint32_t)t * 8u;
        float f[8] = {v0.x, v0.y, v0.z, v0.w, v1.x, v1.y, v1.z, v1.w};
        uint32_t o[4];
#pragma unroll
        for (int p = 0; p < 4; ++p) {
            float a = keep_mask(k0, k1, j + 2 * p)     ? f[2 * p] * 2.f     : 0.f;
            float b = keep_mask(k0, k1, j + 2 * p + 1) ? f[2 * p + 1] * 2.f : 0.f;
            o[p] = f2bf(a) | (f2bf(b) << 16);
        }
        ((uint4*)Xb)[t] = make_uint4(o[0], o[1], o[2], o[3]);
    }
    if (t < 128 * 128 + 64 * 128) {
        if (t < 128 * 128) {
            int n = t >> 7, k = t & 127;
            W1T[n * 128 + k] = (ushort)f2bf(W1[k * 128 + n]);
        } else {
            int u = t - 128 * 128;
            int n = u >> 7, k = u & 127;
            W2T[n * 128 + k] = (ushort)f2bf(W2[k * 64 + n]);
        }
    }
    if (t < N_EDGES) {
        int r = rows[t];
        if (r >= 0 && r < N_NODES) atomicAdd(&deg[r], 1);
    }
}

// ---------------- CSR build ----------------

__global__ __launch_bounds__(CSR_BLK) void degsum_kernel(const int* __restrict__ deg,
                                                         int* __restrict__ blockSums) {
    __shared__ int red[CSR_BLK];
    int idx = blockIdx.x * CSR_BLK + threadIdx.x;
    red[threadIdx.x] = (idx < N_NODES) ? deg[idx] : 0;
    __syncthreads();
    for (int off = CSR_BLK / 2; off > 0; off >>= 1) {
        if (threadIdx.x < off) red[threadIdx.x] += red[threadIdx.x + off];
        __syncthreads();
    }
    if (threadIdx.x == 0) blockSums[blockIdx.x] = red[0];
}

__global__ __launch_bounds__(256) void scanblk_kernel(const int* __restrict__ blockSums,
                                                      int* __restrict__ blockOff) {
    __shared__ int s[256];
    int tid = threadIdx.x;
    s[tid] = (tid < CSR_NBLK) ? blockSums[tid] : 0;
    __syncthreads();
    for (int off = 1; off < 256; off <<= 1) {
        int t = (tid >= off) ? s[tid - off] : 0;
        __syncthreads();
        if (tid >= off) s[tid] += t;
        __syncthreads();
    }
    if (tid < CSR_NBLK) blockOff[tid] = (tid == 0) ? 0 : s[tid - 1];
}

__global__ __launch_bounds__(CSR_BLK) void scanfinal_kernel(const int* __restrict__ deg,
                                                            const int* __restrict__ blockOff,
                                                            int* __restrict__ start,
                                                            int* __restrict__ bcur) {
    __shared__ int s[CSR_BLK];
    int tid = threadIdx.x;
    int idx = blockIdx.x * CSR_BLK + tid;
    int d = (idx < N_NODES) ? deg[idx] : 0;
    s[tid] = d;
    __syncthreads();
    for (int off = 1; off < CSR_BLK; off <<= 1) {
        int t = (tid >= off) ? s[tid - off] : 0;
        __syncthreads();
        if (tid >= off) s[tid] += t;
        __syncthreads();
    }
    int incl = s[tid];
    int excl = incl - d;
    int boff = blockOff[blockIdx.x];
    if (idx < N_NODES) {
        int s0 = boff + excl;
        start[idx] = s0;
        if ((idx & 127) == 0) bcur[idx >> BSH] = s0;
        if (idx == N_NODES - 1) start[N_NODES] = boff + incl;
    }
}

__global__ __launch_bounds__(256) void bucket_scatter(const int* __restrict__ rows,
                                                      const int* __restrict__ cols,
                                                      const float* __restrict__ w,
                                                      int* __restrict__ bcur,
                                                      int* __restrict__ tmpRow,
                                                      int2* __restrict__ tmpCW) {
    __shared__ int hist[NBUCK];
    __shared__ int base[NBUCK];
    int e0 = blockIdx.x * EPB;
    for (int i = threadIdx.x; i < NBUCK; i += 256) hist[i] = 0;
    __syncthreads();
    int myrow[16];
#pragma unroll
    for (int k = 0; k < 16; ++k) {
        int e = e0 + k * 256 + threadIdx.x;
        int r = (e < N_EDGES) ? rows[e] : -1;
        if (r < 0 || r >= N_NODES) r = -1;
        myrow[k] = r;
        if (r >= 0) atomicAdd(&hist[r >> BSH], 1);
    }
    __syncthreads();
    for (int b = threadIdx.x; b < NBUCK; b += 256) {
        int c = hist[b];
        base[b] = (c > 0) ? atomicAdd(&bcur[b], c) : 0;
        hist[b] = 0;
    }
    __syncthreads();
#pragma unroll
    for (int k = 0; k < 16; ++k) {
        int r = myrow[k];
        if (r < 0) continue;
        int e = e0 + k * 256 + threadIdx.x;
        int b = r >> BSH;
        int pos = base[b] + atomicAdd(&hist[b], 1);
        if (pos < 0 || pos >= N_EDGES) continue;
        tmpRow[pos] = r;
        tmpCW[pos] = make_int2(cols[e], __float_as_int(w[e]));
    }
}

__global__ __launch_bounds__(256) void scatter2(const int* __restrict__ start,
                                                const int* __restrict__ tmpRow,
                                                const int2* __restrict__ tmpCW,
                                                int2* __restrict__ epk) {
    __shared__ int lcur[1 << BSH];
    int b = blockIdx.x;
    int r0 = b << BSH;
    int r1 = r0 + (1 << BSH);
    if (r1 > N_NODES) r1 = N_NODES;
    int nr = r1 - r0;
    for (int i = threadIdx.x; i < nr; i += 256) lcur[i] = start[r0 + i];
    __syncthreads();
    int e0 = start[r0], e1 = start[r1];
    for (int i = e0 + threadIdx.x; i < e1; i += 256) {
        int r = tmpRow[i];
        if (r < r0 || r >= r1) continue;
        int pos = atomicAdd(&lcur[r - r0], 1);
        if (pos < 0 || pos >= N_EDGES) continue;
        epk[pos] = tmpCW[i];
    }
}

// ---------------- fused SpMM(128) + MFMA MLP, 512-thread blocks ----------------
// Per block: 64 rows, 8 waves. Phase A: 32 rows concurrent (2 row-groups/thread)
// -> bf16 LDS. ONE barrier. Waves 4-7 exit; waves 0-3 do the MFMA MLP on their
// own 16-row slice (within-wave LDS reuse: no further barriers needed).
#define LROW 136
__global__ __launch_bounds__(512) void spmm_mlp(const int* __restrict__ start,
                                                const int2* __restrict__ epk,
                                                const ushort* __restrict__ Xb,
                                                const ushort* __restrict__ W1T,
                                                const float* __restrict__ b1,
                                                const ushort* __restrict__ W2T,
                                                ushort* __restrict__ T,
                                                uint32_t k0, uint32_t k1) {
    __shared__ ushort shm[64][LROW];     // 17.4 KB: SpMM out, then hidden tile
    int tid = threadIdx.x;
    int rowBase = blockIdx.x * 64;

    // ---- Phase A: SpMM, 32 rows concurrent ----
    {
        int lane = tid & 15;
        int rsub = tid >> 4;   // 0..31
#pragma unroll
        for (int rg = 0; rg < 2; ++rg) {
            int lr = rg * 32 + rsub;
            int r = rowBase + lr;
            float a0[8] = {0.f, 0.f, 0.f, 0.f, 0.f, 0.f, 0.f, 0.f};
            float a1[8] = {0.f, 0.f, 0.f, 0.f, 0.f, 0.f, 0.f, 0.f};
            if (r < N_NODES) {
                int s0 = start[r], s1 = start[r + 1];
                int i = s0;
                for (; i + 4 <= s1; i += 4) {
                    int2 e0 = epk[i], e1 = epk[i + 1], e2 = epk[i + 2], e3 = epk[i + 3];
                    uint4 u0 = *(const uint4*)(Xb + (size_t)e0.x * D + lane * 8);
                    uint4 u1 = *(const uint4*)(Xb + (size_t)e1.x * D + lane * 8);
                    uint4 u2 = *(const uint4*)(Xb + (size_t)e2.x * D + lane * 8);
                    uint4 u3 = *(const uint4*)(Xb + (size_t)e3.x * D + lane * 8);
                    fma8(a0, u0, __int_as_float(e0.y));
                    fma8(a1, u1, __int_as_float(e1.y));
                    fma8(a0, u2, __int_as_float(e2.y));
                    fma8(a1, u3, __int_as_float(e3.y));
                }
                for (; i < s1; ++i) {
                    int2 e = epk[i];
                    uint4 u = *(const uint4*)(Xb + (size_t)e.x * D + lane * 8);
                    fma8(a0, u, __int_as_float(e.y));
                }
            }
            uint4 o;
            o.x = f2bf(a0[0] + a1[0]) | (f2bf(a0[1] + a1[1]) << 16);
            o.y = f2bf(a0[2] + a1[2]) | (f2bf(a0[3] + a1[3]) << 16);
            o.z = f2bf(a0[4] + a1[4]) | (f2bf(a0[5] + a1[5]) << 16);
            o.w = f2bf(a0[6] + a1[6]) | (f2bf(a0[7] + a1[7]) << 16);
            *(uint4*)&shm[lr][lane * 8] = o;
        }
    }
    __syncthreads();   // the ONLY barrier: phase A (8 waves) -> phase B reads

    int wave = tid >> 6;
    if (wave >= 4) return;   // waves 4-7 done (no barriers below)

    // ---- Phase B: MFMA MLP; each wave owns rows [wave*16, wave*16+16) ----
    int lane = tid & 63;
    int lrow = lane & 15;
    int lhk  = lane >> 4;
    int rowB = rowBase + wave * 16;

    bf16x8 afrag[4];
#pragma unroll
    for (int kb = 0; kb < 4; ++kb)
        afrag[kb] = *(const bf16x8*)&shm[wave * 16 + lrow][lhk * 8 + kb * 32];

    f32x4 acc[8];
#pragma unroll
    for (int nt = 0; nt < 8; ++nt) acc[nt] = (f32x4){0.f, 0.f, 0.f, 0.f};
#pragma unroll
    for (int nt = 0; nt < 8; ++nt) {
        const ushort* wp = W1T + (size_t)(nt * 16 + lrow) * 128 + lhk * 8;
#pragma unroll
        for (int kb = 0; kb < 4; ++kb) {
            bf16x8 bfrag = *(const bf16x8*)(wp + kb * 32);
            acc[nt] = __builtin_amdgcn_mfma_f32_16x16x32_bf16(afrag[kb], bfrag, acc[nt], 0, 0, 0);
        }
    }

    // epilogue1 -> hidden tile into this wave's own shm slice (within-wave reuse)
#pragma unroll
    for (int nt = 0; nt < 8; ++nt) {
        int c = nt * 16 + lrow;
        float bias = b1[c];
#pragma unroll
        for (int v = 0; v < 4; ++v) {
            int rl = lhk * 4 + v;
            int row = rowB + rl;
            float x = fmaxf(acc[nt][v] + bias, 0.f);
            uint32_t j = (uint32_t)row * 128u + (uint32_t)c;
            x = keep_mask(k0, k1, j) ? x * 2.f : 0.f;
            shm[wave * 16 + rl][c] = (ushort)f2bf(x);
        }
    }
    // no barrier: write/read within the same wave's slice, lockstep + lgkmcnt

    bf16x8 a2[4];
#pragma unroll
    for (int kb = 0; kb < 4; ++kb)
        a2[kb] = *(const bf16x8*)&shm[wave * 16 + lrow][lhk * 8 + kb * 32];

    f32x4 acc2[4];
#pragma unroll
    for (int nt = 0; nt < 4; ++nt) acc2[nt] = (f32x4){0.f, 0.f, 0.f, 0.f};
#pragma unroll
    for (int nt = 0; nt < 4; ++nt) {
        const ushort* wp = W2T + (size_t)(nt * 16 + lrow) * 128 + lhk * 8;
#pragma unroll
        for (int kb = 0; kb < 4; ++kb) {
            bf16x8 bfrag = *(const bf16x8*)(wp + kb * 32);
            acc2[nt] = __builtin_amdgcn_mfma_f32_16x16x32_bf16(a2[kb], bfrag, acc2[nt], 0, 0, 0);
        }
    }

#pragma unroll
    for (int nt = 0; nt < 4; ++nt) {
        int c = nt * 16 + lrow;
#pragma unroll
        for (int v = 0; v < 4; ++v) {
            int row = rowB + lhk * 4 + v;
            if (row < N_NODES)
                T[(size_t)row * DOUT + c] = (ushort)f2bf(acc2[nt][v]);
        }
    }
}

// ---------------- SpMM 64-wide + bias, bf16 gather -> fp32 out ----------------
__global__ __launch_bounds__(256) void spmm64_bf16(const int* __restrict__ start,
                                                   const int2* __restrict__ epk,
                                                   const ushort* __restrict__ tb,
                                                   const float* __restrict__ b2,
                                                   float* __restrict__ out) {
    int t = blockIdx.x * blockDim.x + threadIdx.x;
    int r = t >> 3;
    if (r >= N_NODES) return;
    int lane = t & 7;
    int s0 = start[r], s1 = start[r + 1];
    float a0[8] = {0.f, 0.f, 0.f, 0.f, 0.f, 0.f, 0.f, 0.f};
    float a1[8] = {0.f, 0.f, 0.f, 0.f, 0.f, 0.f, 0.f, 0.f};
    int i = s0;
    for (; i + 4 <= s1; i += 4) {
        int2 e0 = epk[i], e1 = epk[i + 1], e2 = epk[i + 2], e3 = epk[i + 3];
        uint4 u0 = *(const uint4*)(tb + (size_t)e0.x * DOUT + lane * 8);
        uint4 u1 = *(const uint4*)(tb + (size_t)e1.x * DOUT + lane * 8);
        uint4 u2 = *(const uint4*)(tb + (size_t)e2.x * DOUT + lane * 8);
        uint4 u3 = *(const uint4*)(tb + (size_t)e3.x * DOUT + lane * 8);
        fma8(a0, u0, __int_as_float(e0.y));
        fma8(a1, u1, __int_as_float(e1.y));
        fma8(a0, u2, __int_as_float(e2.y));
        fma8(a1, u3, __int_as_float(e3.y));
    }
    for (; i < s1; ++i) {
        int2 e = epk[i];
        uint4 u = *(const uint4*)(tb + (size_t)e.x * DOUT + lane * 8);
        fma8(a0, u, __int_as_float(e.y));
    }
    float4 blo = *(const float4*)(b2 + lane * 8);
    float4 bhi = *(const float4*)(b2 + lane * 8 + 4);
    float* op = out + (size_t)r * DOUT + lane * 8;
    *(float4*)(op + 0) = make_float4(a0[0] + a1[0] + blo.x, a0[1] + a1[1] + blo.y,
                                     a0[2] + a1[2] + blo.z, a0[3] + a1[3] + blo.w);
    *(float4*)(op + 4) = make_float4(a0[4] + a1[4] + bhi.x, a0[5] + a1[5] + bhi.y,
                                     a0[6] + a1[6] + bhi.z, a0[7] + a1[7] + bhi.w);
}

extern "C" void kernel_launch(void* const* d_in, const int* in_sizes, int n_in,
                              void* d_out, int out_size, void* d_ws, size_t ws_size,
                              hipStream_t stream) {
    const int*   rows = (const int*)d_in[0];
    const int*   cols = (const int*)d_in[1];
    const float* w    = (const float*)d_in[2];
    const float* X    = (const float*)d_in[3];
    const float* W1   = (const float*)d_in[4];
    const float* b1   = (const float*)d_in[5];
    const float* W2   = (const float*)d_in[6];
    const float* b2   = (const float*)d_in[7];
    float* out = (float*)d_out;

    uint32_t ka0, ka1, kb0, kb1;
    threefry2x32(0u, 42u, 0u, 0u, ka0, ka1);  // k1 (drop1)
    threefry2x32(0u, 42u, 0u, 1u, kb0, kb1);  // k2 (drop2)

    // workspace layout
    char* p = (char*)d_ws;
    ushort* Xb        = (ushort*)p;            p += (size_t)N_NODES * D * 2;
    ushort* T         = (ushort*)p;            p += (size_t)N_NODES * DOUT * 2;
    int2*   epk       = (int2*)p;              p += (size_t)N_EDGES * 8;
    int2*   tmpCW     = (int2*)p;              p += (size_t)N_EDGES * 8;
    int*    tmpRow    = (int*)p;               p += (size_t)N_EDGES * 4;
    ushort* W1T       = (ushort*)p;            p += (size_t)128 * 128 * 2;
    ushort* W2T       = (ushort*)p;            p += (size_t)64 * 128 * 2;
    int*    start     = (int*)p;               p += (size_t)(N_NODES + 1) * 4;
    int*    deg       = (int*)p;               p += (size_t)N_NODES * 4;
    int*    bcur      = (int*)p;               p += (size_t)NBUCK * 4;
    int*    blockSums = (int*)p;               p += (size_t)CSR_NBLK * 4;
    int*    blockOff  = (int*)p;               p += (size_t)CSR_NBLK * 4;

    // ---- prologue ----
    hipMemsetAsync(deg, 0, (size_t)N_NODES * 4, stream);
    fused0_kernel<<<(N_EDGES + 255) / 256, 256, 0, stream>>>(X, Xb, W1, W2, W1T, W2T,
                                                             rows, deg, ka0, ka1);
    degsum_kernel<<<CSR_NBLK, CSR_BLK, 0, stream>>>(deg, blockSums);
    scanblk_kernel<<<1, 256, 0, stream>>>(blockSums, blockOff);
    scanfinal_kernel<<<CSR_NBLK, CSR_BLK, 0, stream>>>(deg, blockOff, start, bcur);
    bucket_scatter<<<SC_NBLK, 256, 0, stream>>>(rows, cols, w, bcur, tmpRow, tmpCW);
    scatter2<<<NBUCK, 256, 0, stream>>>(start, tmpRow, tmpCW, epk);

    // ---- forward ----
    spmm_mlp<<<(N_NODES + 63) / 64, 512, 0, stream>>>(start, epk, Xb, W1T, b1, W2T, T, kb0, kb1);
    spmm64_bf16<<<((size_t)N_NODES * 8 + 255) / 256, 256, 0, stream>>>(start, epk, T, b2, out);
}

// Round 16
// 164.965 us; speedup vs baseline: 1.0423x; 1.0423x over previous
//
#include <hip/hip_runtime.h>
#include <stdint.h>

#define N_NODES 50000
#define N_EDGES 800000
#define D 128
#define DOUT 64

#define CSR_BLK 256
#define CSR_NBLK ((N_NODES + CSR_BLK - 1) / CSR_BLK)  // 196

#define BSH 7                                  // rows per bucket = 128
#define NBUCK ((N_NODES + 127) >> BSH)         // 391
#define EPB 4096                               // edges per bucket_scatter block
#define SC_NBLK ((N_EDGES + EPB - 1) / EPB)    // 196

typedef short bf16x8 __attribute__((ext_vector_type(8)));
typedef float f32x4 __attribute__((ext_vector_type(4)));

__host__ __device__ inline uint32_t rotl32(uint32_t v, int d) {
    return (v << d) | (v >> (32 - d));
}

// JAX threefry2x32 (20 rounds), matches jax/_src/prng.py
__host__ __device__ inline void threefry2x32(uint32_t k0, uint32_t k1,
                                             uint32_t x0, uint32_t x1,
                                             uint32_t& o0, uint32_t& o1) {
    uint32_t ks2 = 0x1BD11BDAu ^ k0 ^ k1;
    x0 += k0; x1 += k1;
#define TFR(d) { x0 += x1; x1 = rotl32(x1, d); x1 ^= x0; }
    TFR(13) TFR(15) TFR(26) TFR(6)
    x0 += k1;  x1 += ks2 + 1u;
    TFR(17) TFR(29) TFR(16) TFR(24)
    x0 += ks2; x1 += k0 + 2u;
    TFR(13) TFR(15) TFR(26) TFR(6)
    x0 += k0;  x1 += k1 + 3u;
    TFR(17) TFR(29) TFR(16) TFR(24)
    x0 += k1;  x1 += ks2 + 4u;
    TFR(13) TFR(15) TFR(26) TFR(6)
    x0 += ks2; x1 += k0 + 5u;
#undef TFR
    o0 = x0; o1 = x1;
}

__device__ inline bool keep_mask(uint32_t k0, uint32_t k1, uint32_t j) {
    uint32_t b0, b1;
    threefry2x32(k0, k1, 0u, j, b0, b1);
    uint32_t bits = b0 ^ b1;
    float u = __uint_as_float((bits >> 9) | 0x3f800000u) - 1.0f;
    return u < 0.5f;
}

__device__ inline uint32_t f2bf(float f) {
    uint32_t u = __float_as_uint(f);
    return (u + 0x7fffu + ((u >> 16) & 1u)) >> 16;
}
__device__ inline float bf2f_lo(uint32_t u) { return __uint_as_float(u << 16); }
__device__ inline float bf2f_hi(uint32_t u) { return __uint_as_float(u & 0xffff0000u); }

__device__ inline void fma8(float* a, uint4 u, float w) {
    a[0] = fmaf(w, bf2f_lo(u.x), a[0]);
    a[1] = fmaf(w, bf2f_hi(u.x), a[1]);
    a[2] = fmaf(w, bf2f_lo(u.y), a[2]);
    a[3] = fmaf(w, bf2f_hi(u.y), a[3]);
    a[4] = fmaf(w, bf2f_lo(u.z), a[4]);
    a[5] = fmaf(w, bf2f_hi(u.z), a[5]);
    a[6] = fmaf(w, bf2f_lo(u.w), a[6]);
    a[7] = fmaf(w, bf2f_hi(u.w), a[7]);
}

// ---------------- fused0: dropout(X)->bf16 | weight transpose | degree hist ----------------
__global__ void fused0_kernel(const float* __restrict__ X, ushort* __restrict__ Xb,
                              const float* __restrict__ W1, const float* __restrict__ W2,
                              ushort* __restrict__ W1T, ushort* __restrict__ W2T,
                              const int* __restrict__ rows, int* __restrict__ deg,
                              uint32_t k0, uint32_t k1) {
    int t = blockIdx.x * blockDim.x + threadIdx.x;
    if (t < N_NODES * D / 8) {
        float4 v0 = ((const float4*)X)[t * 2];
        float4 v1 = ((const float4*)X)[t * 2 + 1];
        uint32_t j = (uint32_t)t * 8u;
        float f[8] = {v0.x, v0.y, v0.z, v0.w, v1.x, v1.y, v1.z, v1.w};
        uint32_t o[4];
#pragma unroll
        for (int p = 0; p < 4; ++p) {
            float a = keep_mask(k0, k1, j + 2 * p)     ? f[2 * p] * 2.f     : 0.f;
            float b = keep_mask(k0, k1, j + 2 * p + 1) ? f[2 * p + 1] * 2.f : 0.f;
            o[p] = f2bf(a) | (f2bf(b) << 16);
        }
        ((uint4*)Xb)[t] = make_uint4(o[0], o[1], o[2], o[3]);
    }
    if (t < 128 * 128 + 64 * 128) {
        if (t < 128 * 128) {
            int n = t >> 7, k = t & 127;
            W1T[n * 128 + k] = (ushort)f2bf(W1[k * 128 + n]);
        } else {
            int u = t - 128 * 128;
            int n = u >> 7, k = u & 127;
            W2T[n * 128 + k] = (ushort)f2bf(W2[k * 64 + n]);
        }
    }
    if (t < N_EDGES) {
        int r = rows[t];
        if (r >= 0 && r < N_NODES) atomicAdd(&deg[r], 1);
    }
}

// ---------------- CSR build ----------------

__global__ __launch_bounds__(CSR_BLK) void degsum_kernel(const int* __restrict__ deg,
                                                         int* __restrict__ blockSums) {
    __shared__ int red[CSR_BLK];
    int idx = blockIdx.x * CSR_BLK + threadIdx.x;
    red[threadIdx.x] = (idx < N_NODES) ? deg[idx] : 0;
    __syncthreads();
    for (int off = CSR_BLK / 2; off > 0; off >>= 1) {
        if (threadIdx.x < off) red[threadIdx.x] += red[threadIdx.x + off];
        __syncthreads();
    }
    if (threadIdx.x == 0) blockSums[blockIdx.x] = red[0];
}

__global__ __launch_bounds__(256) void scanblk_kernel(const int* __restrict__ blockSums,
                                                      int* __restrict__ blockOff) {
    __shared__ int s[256];
    int tid = threadIdx.x;
    s[tid] = (tid < CSR_NBLK) ? blockSums[tid] : 0;
    __syncthreads();
    for (int off = 1; off < 256; off <<= 1) {
        int t = (tid >= off) ? s[tid - off] : 0;
        __syncthreads();
        if (tid >= off) s[tid] += t;
        __syncthreads();
    }
    if (tid < CSR_NBLK) blockOff[tid] = (tid == 0) ? 0 : s[tid - 1];
}

__global__ __launch_bounds__(CSR_BLK) void scanfinal_kernel(const int* __restrict__ deg,
                                                            const int* __restrict__ blockOff,
                                                            int* __restrict__ start,
                                                            int* __restrict__ bcur) {
    __shared__ int s[CSR_BLK];
    int tid = threadIdx.x;
    int idx = blockIdx.x * CSR_BLK + tid;
    int d = (idx < N_NODES) ? deg[idx] : 0;
    s[tid] = d;
    __syncthreads();
    for (int off = 1; off < CSR_BLK; off <<= 1) {
        int t = (tid >= off) ? s[tid - off] : 0;
        __syncthreads();
        if (tid >= off) s[tid] += t;
        __syncthreads();
    }
    int incl = s[tid];
    int excl = incl - d;
    int boff = blockOff[blockIdx.x];
    if (idx < N_NODES) {
        int s0 = boff + excl;
        start[idx] = s0;
        if ((idx & 127) == 0) bcur[idx >> BSH] = s0;
        if (idx == N_NODES - 1) start[N_NODES] = boff + incl;
    }
}

__global__ __launch_bounds__(256) void bucket_scatter(const int* __restrict__ rows,
                                                      const int* __restrict__ cols,
                                                      const float* __restrict__ w,
                                                      int* __restrict__ bcur,
                                                      int* __restrict__ tmpRow,
                                                      int2* __restrict__ tmpCW) {
    __shared__ int hist[NBUCK];
    __shared__ int base[NBUCK];
    int e0 = blockIdx.x * EPB;
    for (int i = threadIdx.x; i < NBUCK; i += 256) hist[i] = 0;
    __syncthreads();
    int myrow[16];
#pragma unroll
    for (int k = 0; k < 16; ++k) {
        int e = e0 + k * 256 + threadIdx.x;
        int r = (e < N_EDGES) ? rows[e] : -1;
        if (r < 0 || r >= N_NODES) r = -1;
        myrow[k] = r;
        if (r >= 0) atomicAdd(&hist[r >> BSH], 1);
    }
    __syncthreads();
    for (int b = threadIdx.x; b < NBUCK; b += 256) {
        int c = hist[b];
        base[b] = (c > 0) ? atomicAdd(&bcur[b], c) : 0;
        hist[b] = 0;
    }
    __syncthreads();
#pragma unroll
    for (int k = 0; k < 16; ++k) {
        int r = myrow[k];
        if (r < 0) continue;
        int e = e0 + k * 256 + threadIdx.x;
        int b = r >> BSH;
        int pos = base[b] + atomicAdd(&hist[b], 1);
        if (pos < 0 || pos >= N_EDGES) continue;
        tmpRow[pos] = r;
        tmpCW[pos] = make_int2(cols[e], __float_as_int(w[e]));
    }
}

__global__ __launch_bounds__(256) void scatter2(const int* __restrict__ start,
                                                const int* __restrict__ tmpRow,
                                                const int2* __restrict__ tmpCW,
                                                int2* __restrict__ epk) {
    __shared__ int lcur[1 << BSH];
    int b = blockIdx.x;
    int r0 = b << BSH;
    int r1 = r0 + (1 << BSH);
    if (r1 > N_NODES) r1 = N_NODES;
    int nr = r1 - r0;
    for (int i = threadIdx.x; i < nr; i += 256) lcur[i] = start[r0 + i];
    __syncthreads();
    int e0 = start[r0], e1 = start[r1];
    for (int i = e0 + threadIdx.x; i < e1; i += 256) {
        int r = tmpRow[i];
        if (r < r0 || r >= r1) continue;
        int pos = atomicAdd(&lcur[r - r0], 1);
        if (pos < 0 || pos >= N_EDGES) continue;
        epk[pos] = tmpCW[i];
    }
}

// ---------------- SpMM 128-wide, bf16 gather -> bf16 out (standalone, high-MLP) ----------------
// 16 lanes/row, uint4 (8 bf16) per lane; 3125 blocks -> max gather concurrency
__global__ __launch_bounds__(256) void spmm128_bf16(const int* __restrict__ start,
                                                    const int2* __restrict__ epk,
                                                    const ushort* __restrict__ hb,
                                                    ushort* __restrict__ outb) {
    int t = blockIdx.x * blockDim.x + threadIdx.x;
    int r = t >> 4;
    if (r >= N_NODES) return;
    int lane = t & 15;
    int s0 = start[r], s1 = start[r + 1];
    float a0[8] = {0.f, 0.f, 0.f, 0.f, 0.f, 0.f, 0.f, 0.f};
    float a1[8] = {0.f, 0.f, 0.f, 0.f, 0.f, 0.f, 0.f, 0.f};
    int i = s0;
    for (; i + 4 <= s1; i += 4) {
        int2 e0 = epk[i], e1 = epk[i + 1], e2 = epk[i + 2], e3 = epk[i + 3];
        uint4 u0 = *(const uint4*)(hb + (size_t)e0.x * D + lane * 8);
        uint4 u1 = *(const uint4*)(hb + (size_t)e1.x * D + lane * 8);
        uint4 u2 = *(const uint4*)(hb + (size_t)e2.x * D + lane * 8);
        uint4 u3 = *(const uint4*)(hb + (size_t)e3.x * D + lane * 8);
        fma8(a0, u0, __int_as_float(e0.y));
        fma8(a1, u1, __int_as_float(e1.y));
        fma8(a0, u2, __int_as_float(e2.y));
        fma8(a1, u3, __int_as_float(e3.y));
    }
    for (; i < s1; ++i) {
        int2 e = epk[i];
        uint4 u = *(const uint4*)(hb + (size_t)e.x * D + lane * 8);
        fma8(a0, u, __int_as_float(e.y));
    }
    uint4 o;
    o.x = f2bf(a0[0] + a1[0]) | (f2bf(a0[1] + a1[1]) << 16);
    o.y = f2bf(a0[2] + a1[2]) | (f2bf(a0[3] + a1[3]) << 16);
    o.z = f2bf(a0[4] + a1[4]) | (f2bf(a0[5] + a1[5]) << 16);
    o.w = f2bf(a0[6] + a1[6]) | (f2bf(a0[7] + a1[7]) << 16);
    *(uint4*)(outb + (size_t)r * D + lane * 8) = o;
}

// ---------------- fused MFMA lin1+lin2 (A-frags from global Bb) ----------------
#define LROW 136
__global__ __launch_bounds__(256) void lin12_mfma(const ushort* __restrict__ Bb,
                                                  const ushort* __restrict__ W1T,
                                                  const float* __restrict__ b1,
                                                  const ushort* __restrict__ W2T,
                                                  ushort* __restrict__ T,
                                                  uint32_t k0, uint32_t k1) {
    __shared__ ushort h1[4][16][LROW];
    int wave = threadIdx.x >> 6;
    int lane = threadIdx.x & 63;
    int lrow = lane & 15;
    int lhk  = lane >> 4;
    int rowBase = blockIdx.x * 64 + wave * 16;

    int arow = rowBase + lrow;
    if (arow >= N_NODES) arow = N_NODES - 1;
    const ushort* aptr = Bb + (size_t)arow * D + lhk * 8;
    bf16x8 afrag[4];
#pragma unroll
    for (int kb = 0; kb < 4; ++kb)
        afrag[kb] = *(const bf16x8*)(aptr + kb * 32);

    f32x4 acc[8];
#pragma unroll
    for (int nt = 0; nt < 8; ++nt) acc[nt] = (f32x4){0.f, 0.f, 0.f, 0.f};
#pragma unroll
    for (int nt = 0; nt < 8; ++nt) {
        const ushort* wp = W1T + (size_t)(nt * 16 + lrow) * 128 + lhk * 8;
#pragma unroll
        for (int kb = 0; kb < 4; ++kb) {
            bf16x8 bfrag = *(const bf16x8*)(wp + kb * 32);
            acc[nt] = __builtin_amdgcn_mfma_f32_16x16x32_bf16(afrag[kb], bfrag, acc[nt], 0, 0, 0);
        }
    }

#pragma unroll
    for (int nt = 0; nt < 8; ++nt) {
        int c = nt * 16 + lrow;
        float bias = b1[c];
#pragma unroll
        for (int v = 0; v < 4; ++v) {
            int rl = lhk * 4 + v;
            int row = rowBase + rl;
            float x = fmaxf(acc[nt][v] + bias, 0.f);
            uint32_t j = (uint32_t)row * 128u + (uint32_t)c;
            x = keep_mask(k0, k1, j) ? x * 2.f : 0.f;
            h1[wave][rl][c] = (ushort)f2bf(x);
        }
    }
    __syncthreads();

    bf16x8 a2[4];
#pragma unroll
    for (int kb = 0; kb < 4; ++kb)
        a2[kb] = *(const bf16x8*)&h1[wave][lrow][lhk * 8 + kb * 32];

    f32x4 acc2[4];
#pragma unroll
    for (int nt = 0; nt < 4; ++nt) acc2[nt] = (f32x4){0.f, 0.f, 0.f, 0.f};
#pragma unroll
    for (int nt = 0; nt < 4; ++nt) {
        const ushort* wp = W2T + (size_t)(nt * 16 + lrow) * 128 + lhk * 8;
#pragma unroll
        for (int kb = 0; kb < 4; ++kb) {
            bf16x8 bfrag = *(const bf16x8*)(wp + kb * 32);
            acc2[nt] = __builtin_amdgcn_mfma_f32_16x16x32_bf16(a2[kb], bfrag, acc2[nt], 0, 0, 0);
        }
    }

#pragma unroll
    for (int nt = 0; nt < 4; ++nt) {
        int c = nt * 16 + lrow;
#pragma unroll
        for (int v = 0; v < 4; ++v) {
            int row = rowBase + lhk * 4 + v;
            if (row < N_NODES)
                T[(size_t)row * DOUT + c] = (ushort)f2bf(acc2[nt][v]);
        }
    }
}

// ---------------- SpMM 64-wide + bias, bf16 gather -> fp32 out ----------------
__global__ __launch_bounds__(256) void spmm64_bf16(const int* __restrict__ start,
                                                   const int2* __restrict__ epk,
                                                   const ushort* __restrict__ tb,
                                                   const float* __restrict__ b2,
                                                   float* __restrict__ out) {
    int t = blockIdx.x * blockDim.x + threadIdx.x;
    int r = t >> 3;
    if (r >= N_NODES) return;
    int lane = t & 7;
    int s0 = start[r], s1 = start[r + 1];
    float a0[8] = {0.f, 0.f, 0.f, 0.f, 0.f, 0.f, 0.f, 0.f};
    float a1[8] = {0.f, 0.f, 0.f, 0.f, 0.f, 0.f, 0.f, 0.f};
    int i = s0;
    for (; i + 4 <= s1; i += 4) {
        int2 e0 = epk[i], e1 = epk[i + 1], e2 = epk[i + 2], e3 = epk[i + 3];
        uint4 u0 = *(const uint4*)(tb + (size_t)e0.x * DOUT + lane * 8);
        uint4 u1 = *(const uint4*)(tb + (size_t)e1.x * DOUT + lane * 8);
        uint4 u2 = *(const uint4*)(tb + (size_t)e2.x * DOUT + lane * 8);
        uint4 u3 = *(const uint4*)(tb + (size_t)e3.x * DOUT + lane * 8);
        fma8(a0, u0, __int_as_float(e0.y));
        fma8(a1, u1, __int_as_float(e1.y));
        fma8(a0, u2, __int_as_float(e2.y));
        fma8(a1, u3, __int_as_float(e3.y));
    }
    for (; i < s1; ++i) {
        int2 e = epk[i];
        uint4 u = *(const uint4*)(tb + (size_t)e.x * DOUT + lane * 8);
        fma8(a0, u, __int_as_float(e.y));
    }
    float4 blo = *(const float4*)(b2 + lane * 8);
    float4 bhi = *(const float4*)(b2 + lane * 8 + 4);
    float* op = out + (size_t)r * DOUT + lane * 8;
    *(float4*)(op + 0) = make_float4(a0[0] + a1[0] + blo.x, a0[1] + a1[1] + blo.y,
                                     a0[2] + a1[2] + blo.z, a0[3] + a1[3] + blo.w);
    *(float4*)(op + 4) = make_float4(a0[4] + a1[4] + bhi.x, a0[5] + a1[5] + bhi.y,
                                     a0[6] + a1[6] + bhi.z, a0[7] + a1[7] + bhi.w);
}

extern "C" void kernel_launch(void* const* d_in, const int* in_sizes, int n_in,
                              void* d_out, int out_size, void* d_ws, size_t ws_size,
                              hipStream_t stream) {
    const int*   rows = (const int*)d_in[0];
    const int*   cols = (const int*)d_in[1];
    const float* w    = (const float*)d_in[2];
    const float* X    = (const float*)d_in[3];
    const float* W1   = (const float*)d_in[4];
    const float* b1   = (const float*)d_in[5];
    const float* W2   = (const float*)d_in[6];
    const float* b2   = (const float*)d_in[7];
    float* out = (float*)d_out;

    uint32_t ka0, ka1, kb0, kb1;
    threefry2x32(0u, 42u, 0u, 0u, ka0, ka1);  // k1 (drop1)
    threefry2x32(0u, 42u, 0u, 1u, kb0, kb1);  // k2 (drop2)

    // workspace layout
    char* p = (char*)d_ws;
    ushort* Xb        = (ushort*)p;            p += (size_t)N_NODES * D * 2;
    ushort* Bb        = (ushort*)p;            p += (size_t)N_NODES * D * 2;
    ushort* T         = (ushort*)p;            p += (size_t)N_NODES * DOUT * 2;
    int2*   epk       = (int2*)p;              p += (size_t)N_EDGES * 8;
    int2*   tmpCW     = (int2*)p;              p += (size_t)N_EDGES * 8;
    int*    tmpRow    = (int*)p;               p += (size_t)N_EDGES * 4;
    ushort* W1T       = (ushort*)p;            p += (size_t)128 * 128 * 2;
    ushort* W2T       = (ushort*)p;            p += (size_t)64 * 128 * 2;
    int*    start     = (int*)p;               p += (size_t)(N_NODES + 1) * 4;
    int*    deg       = (int*)p;               p += (size_t)N_NODES * 4;
    int*    bcur      = (int*)p;               p += (size_t)NBUCK * 4;
    int*    blockSums = (int*)p;               p += (size_t)CSR_NBLK * 4;
    int*    blockOff  = (int*)p;               p += (size_t)CSR_NBLK * 4;

    // ---- prologue ----
    hipMemsetAsync(deg, 0, (size_t)N_NODES * 4, stream);
    fused0_kernel<<<(N_EDGES + 255) / 256, 256, 0, stream>>>(X, Xb, W1, W2, W1T, W2T,
                                                             rows, deg, ka0, ka1);
    degsum_kernel<<<CSR_NBLK, CSR_BLK, 0, stream>>>(deg, blockSums);
    scanblk_kernel<<<1, 256, 0, stream>>>(blockSums, blockOff);
    scanfinal_kernel<<<CSR_NBLK, CSR_BLK, 0, stream>>>(deg, blockOff, start, bcur);
    bucket_scatter<<<SC_NBLK, 256, 0, stream>>>(rows, cols, w, bcur, tmpRow, tmpCW);
    scatter2<<<NBUCK, 256, 0, stream>>>(start, tmpRow, tmpCW, epk);

    // ---- forward (split: max gather concurrency) ----
    spmm128_bf16<<<((size_t)N_NODES * 16 + 255) / 256, 256, 0, stream>>>(start, epk, Xb, Bb);
    lin12_mfma<<<(N_NODES + 63) / 64, 256, 0, stream>>>(Bb, W1T, b1, W2T, T, kb0, kb1);
    spmm64_bf16<<<((size_t)N_NODES * 8 + 255) / 256, 256, 0, stream>>>(start, epk, T, b2, out);
}

// Round 17
// 143.867 us; speedup vs baseline: 1.1952x; 1.1467x over previous
//
#include <hip/hip_runtime.h>
#include <stdint.h>

#define N_NODES 50000
#define N_EDGES 800000
#define D 128
#define DOUT 64

#define BSH 7                                  // rows per bucket = 128
#define NBUCK ((N_NODES + 127) >> BSH)         // 391
#define EPB 4096                               // edges per block (hist/scatter)
#define SC_NBLK ((N_EDGES + EPB - 1) / EPB)    // 196

typedef short bf16x8 __attribute__((ext_vector_type(8)));
typedef float f32x4 __attribute__((ext_vector_type(4)));

__host__ __device__ inline uint32_t rotl32(uint32_t v, int d) {
    return (v << d) | (v >> (32 - d));
}

// JAX threefry2x32 (20 rounds), matches jax/_src/prng.py
__host__ __device__ inline void threefry2x32(uint32_t k0, uint32_t k1,
                                             uint32_t x0, uint32_t x1,
                                             uint32_t& o0, uint32_t& o1) {
    uint32_t ks2 = 0x1BD11BDAu ^ k0 ^ k1;
    x0 += k0; x1 += k1;
#define TFR(d) { x0 += x1; x1 = rotl32(x1, d); x1 ^= x0; }
    TFR(13) TFR(15) TFR(26) TFR(6)
    x0 += k1;  x1 += ks2 + 1u;
    TFR(17) TFR(29) TFR(16) TFR(24)
    x0 += ks2; x1 += k0 + 2u;
    TFR(13) TFR(15) TFR(26) TFR(6)
    x0 += k0;  x1 += k1 + 3u;
    TFR(17) TFR(29) TFR(16) TFR(24)
    x0 += k1;  x1 += ks2 + 4u;
    TFR(13) TFR(15) TFR(26) TFR(6)
    x0 += ks2; x1 += k0 + 5u;
#undef TFR
    o0 = x0; o1 = x1;
}

// keep ⟺ u<0.5 ⟺ top bit of (b0^b1)==0  (exact: u = mantissa(bits>>9)*2^-23)
__device__ inline bool keep_mask(uint32_t k0, uint32_t k1, uint32_t j) {
    uint32_t b0, b1;
    threefry2x32(k0, k1, 0u, j, b0, b1);
    return ((int)(b0 ^ b1)) >= 0;
}

__device__ inline uint32_t f2bf(float f) {
    uint32_t u = __float_as_uint(f);
    return (u + 0x7fffu + ((u >> 16) & 1u)) >> 16;
}
__device__ inline float bf2f_lo(uint32_t u) { return __uint_as_float(u << 16); }
__device__ inline float bf2f_hi(uint32_t u) { return __uint_as_float(u & 0xffff0000u); }

__device__ inline void fma8(float* a, uint4 u, float w) {
    a[0] = fmaf(w, bf2f_lo(u.x), a[0]);
    a[1] = fmaf(w, bf2f_hi(u.x), a[1]);
    a[2] = fmaf(w, bf2f_lo(u.y), a[2]);
    a[3] = fmaf(w, bf2f_hi(u.y), a[3]);
    a[4] = fmaf(w, bf2f_lo(u.z), a[4]);
    a[5] = fmaf(w, bf2f_hi(u.z), a[5]);
    a[6] = fmaf(w, bf2f_lo(u.w), a[6]);
    a[7] = fmaf(w, bf2f_hi(u.w), a[7]);
}

// ---------------- fused0: dropout(X)->bf16 (4 elems/thread) | weight transpose ----------------
__global__ void fused0_kernel(const float* __restrict__ X, ushort* __restrict__ Xb,
                              const float* __restrict__ W1, const float* __restrict__ W2,
                              ushort* __restrict__ W1T, ushort* __restrict__ W2T,
                              uint32_t k0, uint32_t k1) {
    int t = blockIdx.x * blockDim.x + threadIdx.x;
    if (t < N_NODES * D / 4) {   // 1.6M threads
        float4 v = ((const float4*)X)[t];
        uint32_t j = (uint32_t)t * 4u;
        float a = keep_mask(k0, k1, j + 0u) ? v.x * 2.f : 0.f;
        float b = keep_mask(k0, k1, j + 1u) ? v.y * 2.f : 0.f;
        float c = keep_mask(k0, k1, j + 2u) ? v.z * 2.f : 0.f;
        float d = keep_mask(k0, k1, j + 3u) ? v.w * 2.f : 0.f;
        uint2 o;
        o.x = f2bf(a) | (f2bf(b) << 16);
        o.y = f2bf(c) | (f2bf(d) << 16);
        ((uint2*)Xb)[t] = o;
    }
    if (t < 128 * 128 + 64 * 128) {
        if (t < 128 * 128) {
            int n = t >> 7, k = t & 127;
            W1T[n * 128 + k] = (ushort)f2bf(W1[k * 128 + n]);
        } else {
            int u = t - 128 * 128;
            int n = u >> 7, k = u & 127;
            W2T[n * 128 + k] = (ushort)f2bf(W2[k * 64 + n]);
        }
    }
}

// ---------------- CSR build (bucket-local, no per-row global atomics) ----------------

// per-block LDS bucket histogram -> 391-int global counters
__global__ __launch_bounds__(256) void bucketcnt_kernel(const int* __restrict__ rows,
                                                        int* __restrict__ bcnt) {
    __shared__ int h[NBUCK];
    for (int i = threadIdx.x; i < NBUCK; i += 256) h[i] = 0;
    __syncthreads();
    int e0 = blockIdx.x * EPB;
#pragma unroll
    for (int k = 0; k < 16; ++k) {
        int e = e0 + k * 256 + threadIdx.x;
        if (e < N_EDGES) {
            int r = rows[e];
            if (r >= 0 && r < N_NODES) atomicAdd(&h[r >> BSH], 1);
        }
    }
    __syncthreads();
    for (int b = threadIdx.x; b < NBUCK; b += 256)
        if (h[b]) atomicAdd(&bcnt[b], h[b]);
}

// single block: scan 391 bucket counts -> bucketOff[0..NBUCK], init bcur
__global__ __launch_bounds__(512) void scanbuck_kernel(const int* __restrict__ bcnt,
                                                       int* __restrict__ bucketOff,
                                                       int* __restrict__ bcur) {
    __shared__ int s[512];
    int tid = threadIdx.x;
    int c = (tid < NBUCK) ? bcnt[tid] : 0;
    s[tid] = c;
    __syncthreads();
    for (int off = 1; off < 512; off <<= 1) {
        int v = (tid >= off) ? s[tid - off] : 0;
        __syncthreads();
        if (tid >= off) s[tid] += v;
        __syncthreads();
    }
    if (tid < NBUCK) {
        int excl = s[tid] - c;
        bucketOff[tid] = excl;
        bcur[tid] = excl;
    }
    if (tid == NBUCK - 1) bucketOff[NBUCK] = s[tid];
}

// route edges into per-bucket contiguous regions
__global__ __launch_bounds__(256) void bucket_scatter(const int* __restrict__ rows,
                                                      const int* __restrict__ cols,
                                                      const float* __restrict__ w,
                                                      int* __restrict__ bcur,
                                                      int* __restrict__ tmpRow,
                                                      int2* __restrict__ tmpCW) {
    __shared__ int hist[NBUCK];
    __shared__ int base[NBUCK];
    int e0 = blockIdx.x * EPB;
    for (int i = threadIdx.x; i < NBUCK; i += 256) hist[i] = 0;
    __syncthreads();
    int myrow[16];
#pragma unroll
    for (int k = 0; k < 16; ++k) {
        int e = e0 + k * 256 + threadIdx.x;
        int r = (e < N_EDGES) ? rows[e] : -1;
        if (r < 0 || r >= N_NODES) r = -1;
        myrow[k] = r;
        if (r >= 0) atomicAdd(&hist[r >> BSH], 1);
    }
    __syncthreads();
    for (int b = threadIdx.x; b < NBUCK; b += 256) {
        int c = hist[b];
        base[b] = (c > 0) ? atomicAdd(&bcur[b], c) : 0;
        hist[b] = 0;
    }
    __syncthreads();
#pragma unroll
    for (int k = 0; k < 16; ++k) {
        int r = myrow[k];
        if (r < 0) continue;
        int e = e0 + k * 256 + threadIdx.x;
        int b = r >> BSH;
        int pos = base[b] + atomicAdd(&hist[b], 1);
        if (pos < 0 || pos >= N_EDGES) continue;
        tmpRow[pos] = r;
        tmpCW[pos] = make_int2(cols[e], __float_as_int(w[e]));
    }
}

// per-bucket: local row counts + scan -> start[], place edges -> epk
__global__ __launch_bounds__(256) void bucket_finalize(const int* __restrict__ bucketOff,
                                                       const int* __restrict__ tmpRow,
                                                       const int2* __restrict__ tmpCW,
                                                       int* __restrict__ start,
                                                       int2* __restrict__ epk) {
    __shared__ int cnt[1 << BSH];
    __shared__ int scn[1 << BSH];
    __shared__ int cur[1 << BSH];
    int b = blockIdx.x;
    int r0 = b << BSH;
    int nr = N_NODES - r0;
    if (nr > (1 << BSH)) nr = 1 << BSH;
    int e0 = bucketOff[b], e1 = bucketOff[b + 1];
    int tid = threadIdx.x;
    for (int i = tid; i < nr; i += 256) cnt[i] = 0;
    __syncthreads();
    for (int i = e0 + tid; i < e1; i += 256) {
        int r = tmpRow[i] - r0;
        if (r >= 0 && r < nr) atomicAdd(&cnt[r], 1);
    }
    __syncthreads();
    int myc = 0;
    if (tid < 128) {
        myc = (tid < nr) ? cnt[tid] : 0;
        scn[tid] = myc;
    }
    __syncthreads();
    for (int off = 1; off < 128; off <<= 1) {
        int v = 0;
        if (tid < 128 && tid >= off) v = scn[tid - off];
        __syncthreads();
        if (tid < 128 && tid >= off) scn[tid] += v;
        __syncthreads();
    }
    if (tid < nr) {
        int excl = scn[tid] - myc;
        start[r0 + tid] = e0 + excl;
        cur[tid] = e0 + excl;
    }
    if (b == NBUCK - 1 && tid == 0) start[N_NODES] = e1;
    __syncthreads();
    for (int i = e0 + tid; i < e1; i += 256) {
        int r = tmpRow[i] - r0;
        if (r < 0 || r >= nr) continue;
        int pos = atomicAdd(&cur[r], 1);
        if (pos < 0 || pos >= N_EDGES) continue;
        epk[pos] = tmpCW[i];
    }
}

// ---------------- SpMM 128-wide, bf16 gather -> bf16 out ----------------
__global__ __launch_bounds__(256) void spmm128_bf16(const int* __restrict__ start,
                                                    const int2* __restrict__ epk,
                                                    const ushort* __restrict__ hb,
                                                    ushort* __restrict__ outb) {
    int t = blockIdx.x * blockDim.x + threadIdx.x;
    int r = t >> 4;
    if (r >= N_NODES) return;
    int lane = t & 15;
    int s0 = start[r], s1 = start[r + 1];
    float a0[8] = {0.f, 0.f, 0.f, 0.f, 0.f, 0.f, 0.f, 0.f};
    float a1[8] = {0.f, 0.f, 0.f, 0.f, 0.f, 0.f, 0.f, 0.f};
    int i = s0;
    for (; i + 4 <= s1; i += 4) {
        int2 e0 = epk[i], e1 = epk[i + 1], e2 = epk[i + 2], e3 = epk[i + 3];
        uint4 u0 = *(const uint4*)(hb + (size_t)e0.x * D + lane * 8);
        uint4 u1 = *(const uint4*)(hb + (size_t)e1.x * D + lane * 8);
        uint4 u2 = *(const uint4*)(hb + (size_t)e2.x * D + lane * 8);
        uint4 u3 = *(const uint4*)(hb + (size_t)e3.x * D + lane * 8);
        fma8(a0, u0, __int_as_float(e0.y));
        fma8(a1, u1, __int_as_float(e1.y));
        fma8(a0, u2, __int_as_float(e2.y));
        fma8(a1, u3, __int_as_float(e3.y));
    }
    for (; i < s1; ++i) {
        int2 e = epk[i];
        uint4 u = *(const uint4*)(hb + (size_t)e.x * D + lane * 8);
        fma8(a0, u, __int_as_float(e.y));
    }
    uint4 o;
    o.x = f2bf(a0[0] + a1[0]) | (f2bf(a0[1] + a1[1]) << 16);
    o.y = f2bf(a0[2] + a1[2]) | (f2bf(a0[3] + a1[3]) << 16);
    o.z = f2bf(a0[4] + a1[4]) | (f2bf(a0[5] + a1[5]) << 16);
    o.w = f2bf(a0[6] + a1[6]) | (f2bf(a0[7] + a1[7]) << 16);
    *(uint4*)(outb + (size_t)r * D + lane * 8) = o;
}

// ---------------- fused MFMA lin1+lin2 ----------------
#define LROW 136
__global__ __launch_bounds__(256) void lin12_mfma(const ushort* __restrict__ Bb,
                                                  const ushort* __restrict__ W1T,
                                                  const float* __restrict__ b1,
                                                  const ushort* __restrict__ W2T,
                                                  ushort* __restrict__ T,
                                                  uint32_t k0, uint32_t k1) {
    __shared__ ushort h1[4][16][LROW];
    int wave = threadIdx.x >> 6;
    int lane = threadIdx.x & 63;
    int lrow = lane & 15;
    int lhk  = lane >> 4;
    int rowBase = blockIdx.x * 64 + wave * 16;

    int arow = rowBase + lrow;
    if (arow >= N_NODES) arow = N_NODES - 1;
    const ushort* aptr = Bb + (size_t)arow * D + lhk * 8;
    bf16x8 afrag[4];
#pragma unroll
    for (int kb = 0; kb < 4; ++kb)
        afrag[kb] = *(const bf16x8*)(aptr + kb * 32);

    f32x4 acc[8];
#pragma unroll
    for (int nt = 0; nt < 8; ++nt) acc[nt] = (f32x4){0.f, 0.f, 0.f, 0.f};
#pragma unroll
    for (int nt = 0; nt < 8; ++nt) {
        const ushort* wp = W1T + (size_t)(nt * 16 + lrow) * 128 + lhk * 8;
#pragma unroll
        for (int kb = 0; kb < 4; ++kb) {
            bf16x8 bfrag = *(const bf16x8*)(wp + kb * 32);
            acc[nt] = __builtin_amdgcn_mfma_f32_16x16x32_bf16(afrag[kb], bfrag, acc[nt], 0, 0, 0);
        }
    }

#pragma unroll
    for (int nt = 0; nt < 8; ++nt) {
        int c = nt * 16 + lrow;
        float bias = b1[c];
#pragma unroll
        for (int v = 0; v < 4; ++v) {
            int rl = lhk * 4 + v;
            int row = rowBase + rl;
            float x = fmaxf(acc[nt][v] + bias, 0.f);
            uint32_t j = (uint32_t)row * 128u + (uint32_t)c;
            x = keep_mask(k0, k1, j) ? x * 2.f : 0.f;
            h1[wave][rl][c] = (ushort)f2bf(x);
        }
    }
    __syncthreads();

    bf16x8 a2[4];
#pragma unroll
    for (int kb = 0; kb < 4; ++kb)
        a2[kb] = *(const bf16x8*)&h1[wave][lrow][lhk * 8 + kb * 32];

    f32x4 acc2[4];
#pragma unroll
    for (int nt = 0; nt < 4; ++nt) acc2[nt] = (f32x4){0.f, 0.f, 0.f, 0.f};
#pragma unroll
    for (int nt = 0; nt < 4; ++nt) {
        const ushort* wp = W2T + (size_t)(nt * 16 + lrow) * 128 + lhk * 8;
#pragma unroll
        for (int kb = 0; kb < 4; ++kb) {
            bf16x8 bfrag = *(const bf16x8*)(wp + kb * 32);
            acc2[nt] = __builtin_amdgcn_mfma_f32_16x16x32_bf16(a2[kb], bfrag, acc2[nt], 0, 0, 0);
        }
    }

#pragma unroll
    for (int nt = 0; nt < 4; ++nt) {
        int c = nt * 16 + lrow;
#pragma unroll
        for (int v = 0; v < 4; ++v) {
            int row = rowBase + lhk * 4 + v;
            if (row < N_NODES)
                T[(size_t)row * DOUT + c] = (ushort)f2bf(acc2[nt][v]);
        }
    }
}

// ---------------- SpMM 64-wide + bias, bf16 gather -> fp32 out ----------------
__global__ __launch_bounds__(256) void spmm64_bf16(const int* __restrict__ start,
                                                   const int2* __restrict__ epk,
                                                   const ushort* __restrict__ tb,
                                                   const float* __restrict__ b2,
                                                   float* __restrict__ out) {
    int t = blockIdx.x * blockDim.x + threadIdx.x;
    int r = t >> 3;
    if (r >= N_NODES) return;
    int lane = t & 7;
    int s0 = start[r], s1 = start[r + 1];
    float a0[8] = {0.f, 0.f, 0.f, 0.f, 0.f, 0.f, 0.f, 0.f};
    float a1[8] = {0.f, 0.f, 0.f, 0.f, 0.f, 0.f, 0.f, 0.f};
    int i = s0;
    for (; i + 4 <= s1; i += 4) {
        int2 e0 = epk[i], e1 = epk[i + 1], e2 = epk[i + 2], e3 = epk[i + 3];
        uint4 u0 = *(const uint4*)(tb + (size_t)e0.x * DOUT + lane * 8);
        uint4 u1 = *(const uint4*)(tb + (size_t)e1.x * DOUT + lane * 8);
        uint4 u2 = *(const uint4*)(tb + (size_t)e2.x * DOUT + lane * 8);
        uint4 u3 = *(const uint4*)(tb + (size_t)e3.x * DOUT + lane * 8);
        fma8(a0, u0, __int_as_float(e0.y));
        fma8(a1, u1, __int_as_float(e1.y));
        fma8(a0, u2, __int_as_float(e2.y));
        fma8(a1, u3, __int_as_float(e3.y));
    }
    for (; i < s1; ++i) {
        int2 e = epk[i];
        uint4 u = *(const uint4*)(tb + (size_t)e.x * DOUT + lane * 8);
        fma8(a0, u, __int_as_float(e.y));
    }
    float4 blo = *(const float4*)(b2 + lane * 8);
    float4 bhi = *(const float4*)(b2 + lane * 8 + 4);
    float* op = out + (size_t)r * DOUT + lane * 8;
    *(float4*)(op + 0) = make_float4(a0[0] + a1[0] + blo.x, a0[1] + a1[1] + blo.y,
                                     a0[2] + a1[2] + blo.z, a0[3] + a1[3] + blo.w);
    *(float4*)(op + 4) = make_float4(a0[4] + a1[4] + bhi.x, a0[5] + a1[5] + bhi.y,
                                     a0[6] + a1[6] + bhi.z, a0[7] + a1[7] + bhi.w);
}

extern "C" void kernel_launch(void* const* d_in, const int* in_sizes, int n_in,
                              void* d_out, int out_size, void* d_ws, size_t ws_size,
                              hipStream_t stream) {
    const int*   rows = (const int*)d_in[0];
    const int*   cols = (const int*)d_in[1];
    const float* w    = (const float*)d_in[2];
    const float* X    = (const float*)d_in[3];
    const float* W1   = (const float*)d_in[4];
    const float* b1   = (const float*)d_in[5];
    const float* W2   = (const float*)d_in[6];
    const float* b2   = (const float*)d_in[7];
    float* out = (float*)d_out;

    uint32_t ka0, ka1, kb0, kb1;
    threefry2x32(0u, 42u, 0u, 0u, ka0, ka1);  // k1 (drop1)
    threefry2x32(0u, 42u, 0u, 1u, kb0, kb1);  // k2 (drop2)

    // workspace layout
    char* p = (char*)d_ws;
    ushort* Xb        = (ushort*)p;            p += (size_t)N_NODES * D * 2;
    ushort* Bb        = (ushort*)p;            p += (size_t)N_NODES * D * 2;
    ushort* T         = (ushort*)p;            p += (size_t)N_NODES * DOUT * 2;
    int2*   epk       = (int2*)p;              p += (size_t)N_EDGES * 8;
    int2*   tmpCW     = (int2*)p;              p += (size_t)N_EDGES * 8;
    int*    tmpRow    = (int*)p;               p += (size_t)N_EDGES * 4;
    ushort* W1T       = (ushort*)p;            p += (size_t)128 * 128 * 2;
    ushort* W2T       = (ushort*)p;            p += (size_t)64 * 128 * 2;
    int*    start     = (int*)p;               p += (size_t)(N_NODES + 1) * 4;
    int*    bcnt      = (int*)p;               p += (size_t)NBUCK * 4;
    int*    bucketOff = (int*)p;               p += (size_t)(NBUCK + 1) * 4;
    int*    bcur      = (int*)p;               p += (size_t)NBUCK * 4;

    // ---- prologue ----
    hipMemsetAsync(bcnt, 0, (size_t)NBUCK * 4, stream);
    fused0_kernel<<<(N_NODES * D / 4 + 255) / 256, 256, 0, stream>>>(X, Xb, W1, W2, W1T, W2T,
                                                                     ka0, ka1);
    bucketcnt_kernel<<<SC_NBLK, 256, 0, stream>>>(rows, bcnt);
    scanbuck_kernel<<<1, 512, 0, stream>>>(bcnt, bucketOff, bcur);
    bucket_scatter<<<SC_NBLK, 256, 0, stream>>>(rows, cols, w, bcur, tmpRow, tmpCW);
    bucket_finalize<<<NBUCK, 256, 0, stream>>>(bucketOff, tmpRow, tmpCW, start, epk);

    // ---- forward ----
    spmm128_bf16<<<((size_t)N_NODES * 16 + 255) / 256, 256, 0, stream>>>(start, epk, Xb, Bb);
    lin12_mfma<<<(N_NODES + 63) / 64, 256, 0, stream>>>(Bb, W1T, b1, W2T, T, kb0, kb1);
    spmm64_bf16<<<((size_t)N_NODES * 8 + 255) / 256, 256, 0, stream>>>(start, epk, T, b2, out);
}

// Round 18
// 124.948 us; speedup vs baseline: 1.3762x; 1.1514x over previous
//
#include <hip/hip_runtime.h>
#include <stdint.h>

#define N_NODES 50000
#define N_EDGES 800000
#define D 128
#define DOUT 64

#define BSH 7                                  // rows per bucket = 128
#define NBUCK ((N_NODES + 127) >> BSH)         // 391
#define CAP 2560                               // slots per bucket (E[cnt]=2048, +11 sigma)
#define EPB 4096                               // edges per scatter block
#define SC_NBLK ((N_EDGES + EPB - 1) / EPB)    // 196

typedef short bf16x8 __attribute__((ext_vector_type(8)));
typedef float f32x4 __attribute__((ext_vector_type(4)));

__host__ __device__ inline uint32_t rotl32(uint32_t v, int d) {
    return (v << d) | (v >> (32 - d));
}

// JAX threefry2x32 (20 rounds), matches jax/_src/prng.py
__host__ __device__ inline void threefry2x32(uint32_t k0, uint32_t k1,
                                             uint32_t x0, uint32_t x1,
                                             uint32_t& o0, uint32_t& o1) {
    uint32_t ks2 = 0x1BD11BDAu ^ k0 ^ k1;
    x0 += k0; x1 += k1;
#define TFR(d) { x0 += x1; x1 = rotl32(x1, d); x1 ^= x0; }
    TFR(13) TFR(15) TFR(26) TFR(6)
    x0 += k1;  x1 += ks2 + 1u;
    TFR(17) TFR(29) TFR(16) TFR(24)
    x0 += ks2; x1 += k0 + 2u;
    TFR(13) TFR(15) TFR(26) TFR(6)
    x0 += k0;  x1 += k1 + 3u;
    TFR(17) TFR(29) TFR(16) TFR(24)
    x0 += k1;  x1 += ks2 + 4u;
    TFR(13) TFR(15) TFR(26) TFR(6)
    x0 += ks2; x1 += k0 + 5u;
#undef TFR
    o0 = x0; o1 = x1;
}

// keep ⟺ u<0.5 ⟺ top bit of (b0^b1)==0
__device__ inline bool keep_mask(uint32_t k0, uint32_t k1, uint32_t j) {
    uint32_t b0, b1;
    threefry2x32(k0, k1, 0u, j, b0, b1);
    return ((int)(b0 ^ b1)) >= 0;
}

__device__ inline uint32_t f2bf(float f) {
    uint32_t u = __float_as_uint(f);
    return (u + 0x7fffu + ((u >> 16) & 1u)) >> 16;
}
__device__ inline float bf2f_lo(uint32_t u) { return __uint_as_float(u << 16); }
__device__ inline float bf2f_hi(uint32_t u) { return __uint_as_float(u & 0xffff0000u); }

__device__ inline void fma8(float* a, uint4 u, float w) {
    a[0] = fmaf(w, bf2f_lo(u.x), a[0]);
    a[1] = fmaf(w, bf2f_hi(u.x), a[1]);
    a[2] = fmaf(w, bf2f_lo(u.y), a[2]);
    a[3] = fmaf(w, bf2f_hi(u.y), a[3]);
    a[4] = fmaf(w, bf2f_lo(u.z), a[4]);
    a[5] = fmaf(w, bf2f_hi(u.z), a[5]);
    a[6] = fmaf(w, bf2f_lo(u.w), a[6]);
    a[7] = fmaf(w, bf2f_hi(u.w), a[7]);
}

// ---------------- fused0: dropout(X)->bf16 | weight transpose | zero bcnt ----------------
__global__ void fused0_kernel(const float* __restrict__ X, ushort* __restrict__ Xb,
                              const float* __restrict__ W1, const float* __restrict__ W2,
                              ushort* __restrict__ W1T, ushort* __restrict__ W2T,
                              int* __restrict__ bcnt,
                              uint32_t k0, uint32_t k1) {
    int t = blockIdx.x * blockDim.x + threadIdx.x;
    if (t < N_NODES * D / 4) {   // 1.6M threads
        float4 v = ((const float4*)X)[t];
        uint32_t j = (uint32_t)t * 4u;
        float a = keep_mask(k0, k1, j + 0u) ? v.x * 2.f : 0.f;
        float b = keep_mask(k0, k1, j + 1u) ? v.y * 2.f : 0.f;
        float c = keep_mask(k0, k1, j + 2u) ? v.z * 2.f : 0.f;
        float d = keep_mask(k0, k1, j + 3u) ? v.w * 2.f : 0.f;
        uint2 o;
        o.x = f2bf(a) | (f2bf(b) << 16);
        o.y = f2bf(c) | (f2bf(d) << 16);
        ((uint2*)Xb)[t] = o;
    }
    if (t < 128 * 128 + 64 * 128) {
        if (t < 128 * 128) {
            int n = t >> 7, k = t & 127;
            W1T[n * 128 + k] = (ushort)f2bf(W1[k * 128 + n]);
        } else {
            int u = t - 128 * 128;
            int n = u >> 7, k = u & 127;
            W2T[n * 128 + k] = (ushort)f2bf(W2[k * 64 + n]);
        }
    }
    if (t < NBUCK) bcnt[t] = 0;
}

// ---------------- CSR build: one-pass bucket scatter + per-bucket finalize ----------------

// route edges into per-bucket fixed-capacity regions [b*CAP, ...)
__global__ __launch_bounds__(256) void bucket_scatter(const int* __restrict__ rows,
                                                      const int* __restrict__ cols,
                                                      const float* __restrict__ w,
                                                      int* __restrict__ bcnt,
                                                      int* __restrict__ tmpRow,
                                                      int2* __restrict__ tmpCW) {
    __shared__ int hist[NBUCK];
    __shared__ int base[NBUCK];
    int e0 = blockIdx.x * EPB;
    for (int i = threadIdx.x; i < NBUCK; i += 256) hist[i] = 0;
    __syncthreads();
    int myrow[16];
#pragma unroll
    for (int k = 0; k < 16; ++k) {
        int e = e0 + k * 256 + threadIdx.x;
        int r = (e < N_EDGES) ? rows[e] : -1;
        if (r < 0 || r >= N_NODES) r = -1;   // defensive
        myrow[k] = r;
        if (r >= 0) atomicAdd(&hist[r >> BSH], 1);
    }
    __syncthreads();
    for (int b = threadIdx.x; b < NBUCK; b += 256) {
        int c = hist[b];
        base[b] = (c > 0) ? atomicAdd(&bcnt[b], c) : 0;   // reserve range in bucket region
        hist[b] = 0;   // reuse as running offset
    }
    __syncthreads();
#pragma unroll
    for (int k = 0; k < 16; ++k) {
        int r = myrow[k];
        if (r < 0) continue;
        int e = e0 + k * 256 + threadIdx.x;
        int b = r >> BSH;
        int pos = base[b] + atomicAdd(&hist[b], 1);
        if (pos < 0 || pos >= CAP) continue;   // defensive: never overflow bucket region
        int slot = b * CAP + pos;
        tmpRow[slot] = r;
        tmpCW[slot] = make_int2(cols[e], __float_as_int(w[e]));
    }
}

// per-bucket: local row counts + scan -> rowRange[], place edges -> epk (bucket-padded)
__global__ __launch_bounds__(256) void bucket_finalize(const int* __restrict__ bcnt,
                                                       const int* __restrict__ tmpRow,
                                                       const int2* __restrict__ tmpCW,
                                                       int2* __restrict__ rowRange,
                                                       int2* __restrict__ epk) {
    __shared__ int cnt[1 << BSH];
    __shared__ int scn[1 << BSH];
    __shared__ int cur[1 << BSH];
    int b = blockIdx.x;
    int r0 = b << BSH;
    int nr = N_NODES - r0;
    if (nr > (1 << BSH)) nr = 1 << BSH;
    int cb = bcnt[b];
    if (cb > CAP) cb = CAP;   // defensive
    int base = b * CAP;
    int tid = threadIdx.x;
    for (int i = tid; i < nr; i += 256) cnt[i] = 0;
    __syncthreads();
    for (int i = tid; i < cb; i += 256) {
        int r = tmpRow[base + i] - r0;
        if (r >= 0 && r < nr) atomicAdd(&cnt[r], 1);
    }
    __syncthreads();
    int myc = 0;
    if (tid < 128) {
        myc = (tid < nr) ? cnt[tid] : 0;
        scn[tid] = myc;
    }
    __syncthreads();
    for (int off = 1; off < 128; off <<= 1) {
        int v = 0;
        if (tid < 128 && tid >= off) v = scn[tid - off];
        __syncthreads();
        if (tid < 128 && tid >= off) scn[tid] += v;
        __syncthreads();
    }
    if (tid < nr) {
        int excl = scn[tid] - myc;
        rowRange[r0 + tid] = make_int2(base + excl, base + excl + myc);
        cur[tid] = base + excl;
    }
    __syncthreads();
    for (int i = tid; i < cb; i += 256) {
        int r = tmpRow[base + i] - r0;
        if (r < 0 || r >= nr) continue;
        int pos = atomicAdd(&cur[r], 1);
        if (pos < 0 || pos >= NBUCK * CAP) continue;   // defensive
        epk[pos] = tmpCW[base + i];
    }
}

// ---------------- SpMM 128-wide, bf16 gather -> bf16 out ----------------
__global__ __launch_bounds__(256) void spmm128_bf16(const int2* __restrict__ rowRange,
                                                    const int2* __restrict__ epk,
                                                    const ushort* __restrict__ hb,
                                                    ushort* __restrict__ outb) {
    int t = blockIdx.x * blockDim.x + threadIdx.x;
    int r = t >> 4;
    if (r >= N_NODES) return;
    int lane = t & 15;
    int2 rr = rowRange[r];
    int s0 = rr.x, s1 = rr.y;
    float a0[8] = {0.f, 0.f, 0.f, 0.f, 0.f, 0.f, 0.f, 0.f};
    float a1[8] = {0.f, 0.f, 0.f, 0.f, 0.f, 0.f, 0.f, 0.f};
    int i = s0;
    for (; i + 4 <= s1; i += 4) {
        int2 e0 = epk[i], e1 = epk[i + 1], e2 = epk[i + 2], e3 = epk[i + 3];
        uint4 u0 = *(const uint4*)(hb + (size_t)e0.x * D + lane * 8);
        uint4 u1 = *(const uint4*)(hb + (size_t)e1.x * D + lane * 8);
        uint4 u2 = *(const uint4*)(hb + (size_t)e2.x * D + lane * 8);
        uint4 u3 = *(const uint4*)(hb + (size_t)e3.x * D + lane * 8);
        fma8(a0, u0, __int_as_float(e0.y));
        fma8(a1, u1, __int_as_float(e1.y));
        fma8(a0, u2, __int_as_float(e2.y));
        fma8(a1, u3, __int_as_float(e3.y));
    }
    for (; i < s1; ++i) {
        int2 e = epk[i];
        uint4 u = *(const uint4*)(hb + (size_t)e.x * D + lane * 8);
        fma8(a0, u, __int_as_float(e.y));
    }
    uint4 o;
    o.x = f2bf(a0[0] + a1[0]) | (f2bf(a0[1] + a1[1]) << 16);
    o.y = f2bf(a0[2] + a1[2]) | (f2bf(a0[3] + a1[3]) << 16);
    o.z = f2bf(a0[4] + a1[4]) | (f2bf(a0[5] + a1[5]) << 16);
    o.w = f2bf(a0[6] + a1[6]) | (f2bf(a0[7] + a1[7]) << 16);
    *(uint4*)(outb + (size_t)r * D + lane * 8) = o;
}

// ---------------- fused MFMA lin1+lin2 ----------------
#define LROW 136
__global__ __launch_bounds__(256) void lin12_mfma(const ushort* __restrict__ Bb,
                                                  const ushort* __restrict__ W1T,
                                                  const float* __restrict__ b1,
                                                  const ushort* __restrict__ W2T,
                                                  ushort* __restrict__ T,
                                                  uint32_t k0, uint32_t k1) {
    __shared__ ushort h1[4][16][LROW];
    int wave = threadIdx.x >> 6;
    int lane = threadIdx.x & 63;
    int lrow = lane & 15;
    int lhk  = lane >> 4;
    int rowBase = blockIdx.x * 64 + wave * 16;

    int arow = rowBase + lrow;
    if (arow >= N_NODES) arow = N_NODES - 1;
    const ushort* aptr = Bb + (size_t)arow * D + lhk * 8;
    bf16x8 afrag[4];
#pragma unroll
    for (int kb = 0; kb < 4; ++kb)
        afrag[kb] = *(const bf16x8*)(aptr + kb * 32);

    f32x4 acc[8];
#pragma unroll
    for (int nt = 0; nt < 8; ++nt) acc[nt] = (f32x4){0.f, 0.f, 0.f, 0.f};
#pragma unroll
    for (int nt = 0; nt < 8; ++nt) {
        const ushort* wp = W1T + (size_t)(nt * 16 + lrow) * 128 + lhk * 8;
#pragma unroll
        for (int kb = 0; kb < 4; ++kb) {
            bf16x8 bfrag = *(const bf16x8*)(wp + kb * 32);
            acc[nt] = __builtin_amdgcn_mfma_f32_16x16x32_bf16(afrag[kb], bfrag, acc[nt], 0, 0, 0);
        }
    }

#pragma unroll
    for (int nt = 0; nt < 8; ++nt) {
        int c = nt * 16 + lrow;
        float bias = b1[c];
#pragma unroll
        for (int v = 0; v < 4; ++v) {
            int rl = lhk * 4 + v;
            int row = rowBase + rl;
            float x = fmaxf(acc[nt][v] + bias, 0.f);
            uint32_t j = (uint32_t)row * 128u + (uint32_t)c;
            x = keep_mask(k0, k1, j) ? x * 2.f : 0.f;
            h1[wave][rl][c] = (ushort)f2bf(x);
        }
    }
    __syncthreads();

    bf16x8 a2[4];
#pragma unroll
    for (int kb = 0; kb < 4; ++kb)
        a2[kb] = *(const bf16x8*)&h1[wave][lrow][lhk * 8 + kb * 32];

    f32x4 acc2[4];
#pragma unroll
    for (int nt = 0; nt < 4; ++nt) acc2[nt] = (f32x4){0.f, 0.f, 0.f, 0.f};
#pragma unroll
    for (int nt = 0; nt < 4; ++nt) {
        const ushort* wp = W2T + (size_t)(nt * 16 + lrow) * 128 + lhk * 8;
#pragma unroll
        for (int kb = 0; kb < 4; ++kb) {
            bf16x8 bfrag = *(const bf16x8*)(wp + kb * 32);
            acc2[nt] = __builtin_amdgcn_mfma_f32_16x16x32_bf16(a2[kb], bfrag, acc2[nt], 0, 0, 0);
        }
    }

#pragma unroll
    for (int nt = 0; nt < 4; ++nt) {
        int c = nt * 16 + lrow;
#pragma unroll
        for (int v = 0; v < 4; ++v) {
            int row = rowBase + lhk * 4 + v;
            if (row < N_NODES)
                T[(size_t)row * DOUT + c] = (ushort)f2bf(acc2[nt][v]);
        }
    }
}

// ---------------- SpMM 64-wide + bias, bf16 gather -> fp32 out ----------------
__global__ __launch_bounds__(256) void spmm64_bf16(const int2* __restrict__ rowRange,
                                                   const int2* __restrict__ epk,
                                                   const ushort* __restrict__ tb,
                                                   const float* __restrict__ b2,
                                                   float* __restrict__ out) {
    int t = blockIdx.x * blockDim.x + threadIdx.x;
    int r = t >> 3;
    if (r >= N_NODES) return;
    int lane = t & 7;
    int2 rr = rowRange[r];
    int s0 = rr.x, s1 = rr.y;
    float a0[8] = {0.f, 0.f, 0.f, 0.f, 0.f, 0.f, 0.f, 0.f};
    float a1[8] = {0.f, 0.f, 0.f, 0.f, 0.f, 0.f, 0.f, 0.f};
    int i = s0;
    for (; i + 4 <= s1; i += 4) {
        int2 e0 = epk[i], e1 = epk[i + 1], e2 = epk[i + 2], e3 = epk[i + 3];
        uint4 u0 = *(const uint4*)(tb + (size_t)e0.x * DOUT + lane * 8);
        uint4 u1 = *(const uint4*)(tb + (size_t)e1.x * DOUT + lane * 8);
        uint4 u2 = *(const uint4*)(tb + (size_t)e2.x * DOUT + lane * 8);
        uint4 u3 = *(const uint4*)(tb + (size_t)e3.x * DOUT + lane * 8);
        fma8(a0, u0, __int_as_float(e0.y));
        fma8(a1, u1, __int_as_float(e1.y));
        fma8(a0, u2, __int_as_float(e2.y));
        fma8(a1, u3, __int_as_float(e3.y));
    }
    for (; i < s1; ++i) {
        int2 e = epk[i];
        uint4 u = *(const uint4*)(tb + (size_t)e.x * DOUT + lane * 8);
        fma8(a0, u, __int_as_float(e.y));
    }
    float4 blo = *(const float4*)(b2 + lane * 8);
    float4 bhi = *(const float4*)(b2 + lane * 8 + 4);
    float* op = out + (size_t)r * DOUT + lane * 8;
    *(float4*)(op + 0) = make_float4(a0[0] + a1[0] + blo.x, a0[1] + a1[1] + blo.y,
                                     a0[2] + a1[2] + blo.z, a0[3] + a1[3] + blo.w);
    *(float4*)(op + 4) = make_float4(a0[4] + a1[4] + bhi.x, a0[5] + a1[5] + bhi.y,
                                     a0[6] + a1[6] + bhi.z, a0[7] + a1[7] + bhi.w);
}

extern "C" void kernel_launch(void* const* d_in, const int* in_sizes, int n_in,
                              void* d_out, int out_size, void* d_ws, size_t ws_size,
                              hipStream_t stream) {
    const int*   rows = (const int*)d_in[0];
    const int*   cols = (const int*)d_in[1];
    const float* w    = (const float*)d_in[2];
    const float* X    = (const float*)d_in[3];
    const float* W1   = (const float*)d_in[4];
    const float* b1   = (const float*)d_in[5];
    const float* W2   = (const float*)d_in[6];
    const float* b2   = (const float*)d_in[7];
    float* out = (float*)d_out;

    uint32_t ka0, ka1, kb0, kb1;
    threefry2x32(0u, 42u, 0u, 0u, ka0, ka1);  // k1 (drop1)
    threefry2x32(0u, 42u, 0u, 1u, kb0, kb1);  // k2 (drop2)

    // workspace layout
    char* p = (char*)d_ws;
    ushort* Xb        = (ushort*)p;            p += (size_t)N_NODES * D * 2;        // 12.8 MB
    ushort* Bb        = (ushort*)p;            p += (size_t)N_NODES * D * 2;        // 12.8 MB
    ushort* T         = (ushort*)p;            p += (size_t)N_NODES * DOUT * 2;     // 6.4 MB
    int2*   epk       = (int2*)p;              p += (size_t)NBUCK * CAP * 8;        // 8.0 MB
    int2*   tmpCW     = (int2*)p;              p += (size_t)NBUCK * CAP * 8;        // 8.0 MB
    int*    tmpRow    = (int*)p;               p += (size_t)NBUCK * CAP * 4;        // 4.0 MB
    int2*   rowRange  = (int2*)p;              p += (size_t)N_NODES * 8;            // 0.4 MB
    ushort* W1T       = (ushort*)p;            p += (size_t)128 * 128 * 2;
    ushort* W2T       = (ushort*)p;            p += (size_t)64 * 128 * 2;
    int*    bcnt      = (int*)p;               p += (size_t)NBUCK * 4;

    // ---- prologue (3 dispatches) ----
    fused0_kernel<<<(N_NODES * D / 4 + 255) / 256, 256, 0, stream>>>(X, Xb, W1, W2, W1T, W2T,
                                                                     bcnt, ka0, ka1);
    bucket_scatter<<<SC_NBLK, 256, 0, stream>>>(rows, cols, w, bcnt, tmpRow, tmpCW);
    bucket_finalize<<<NBUCK, 256, 0, stream>>>(bcnt, tmpRow, tmpCW, rowRange, epk);

    // ---- forward (3 dispatches) ----
    spmm128_bf16<<<((size_t)N_NODES * 16 + 255) / 256, 256, 0, stream>>>(rowRange, epk, Xb, Bb);
    lin12_mfma<<<(N_NODES + 63) / 64, 256, 0, stream>>>(Bb, W1T, b1, W2T, T, kb0, kb1);
    spmm64_bf16<<<((size_t)N_NODES * 8 + 255) / 256, 256, 0, stream>>>(rowRange, epk, T, b2, out);
}

// Round 19
// 122.247 us; speedup vs baseline: 1.4066x; 1.0221x over previous
//
#include <hip/hip_runtime.h>
#include <stdint.h>

#define N_NODES 50000
#define N_EDGES 800000
#define D 128
#define DOUT 64

#define BSH 7                                  // rows per bucket = 128
#define NBUCK ((N_NODES + 127) >> BSH)         // 391
#define CAP 2560                               // slots per bucket
#define EPB 4096                               // edges per scatter block
#define SC_NBLK ((N_EDGES + EPB - 1) / EPB)    // 196
#define DROP_NBLK ((N_NODES * D / 4 + 255) / 256)  // 6250

typedef short bf16x8 __attribute__((ext_vector_type(8)));
typedef float f32x4 __attribute__((ext_vector_type(4)));

__host__ __device__ inline uint32_t rotl32(uint32_t v, int d) {
    return (v << d) | (v >> (32 - d));
}

// JAX threefry2x32 (20 rounds), matches jax/_src/prng.py
__host__ __device__ inline void threefry2x32(uint32_t k0, uint32_t k1,
                                             uint32_t x0, uint32_t x1,
                                             uint32_t& o0, uint32_t& o1) {
    uint32_t ks2 = 0x1BD11BDAu ^ k0 ^ k1;
    x0 += k0; x1 += k1;
#define TFR(d) { x0 += x1; x1 = rotl32(x1, d); x1 ^= x0; }
    TFR(13) TFR(15) TFR(26) TFR(6)
    x0 += k1;  x1 += ks2 + 1u;
    TFR(17) TFR(29) TFR(16) TFR(24)
    x0 += ks2; x1 += k0 + 2u;
    TFR(13) TFR(15) TFR(26) TFR(6)
    x0 += k0;  x1 += k1 + 3u;
    TFR(17) TFR(29) TFR(16) TFR(24)
    x0 += k1;  x1 += ks2 + 4u;
    TFR(13) TFR(15) TFR(26) TFR(6)
    x0 += ks2; x1 += k0 + 5u;
#undef TFR
    o0 = x0; o1 = x1;
}

// keep ⟺ u<0.5 ⟺ top bit of (b0^b1)==0
__device__ inline bool keep_mask(uint32_t k0, uint32_t k1, uint32_t j) {
    uint32_t b0, b1;
    threefry2x32(k0, k1, 0u, j, b0, b1);
    return ((int)(b0 ^ b1)) >= 0;
}

__device__ inline uint32_t f2bf(float f) {
    uint32_t u = __float_as_uint(f);
    return (u + 0x7fffu + ((u >> 16) & 1u)) >> 16;
}
__device__ inline float bf2f_lo(uint32_t u) { return __uint_as_float(u << 16); }
__device__ inline float bf2f_hi(uint32_t u) { return __uint_as_float(u & 0xffff0000u); }

__device__ inline void fma8(float* a, uint4 u, float w) {
    a[0] = fmaf(w, bf2f_lo(u.x), a[0]);
    a[1] = fmaf(w, bf2f_hi(u.x), a[1]);
    a[2] = fmaf(w, bf2f_lo(u.y), a[2]);
    a[3] = fmaf(w, bf2f_hi(u.y), a[3]);
    a[4] = fmaf(w, bf2f_lo(u.z), a[4]);
    a[5] = fmaf(w, bf2f_hi(u.z), a[5]);
    a[6] = fmaf(w, bf2f_lo(u.w), a[6]);
    a[7] = fmaf(w, bf2f_hi(u.w), a[7]);
}

// ---------------- fusedA: bucket scatter (blocks 0..195) | dropout+weights (rest) ----------------
__global__ __launch_bounds__(256) void fusedA_kernel(const int* __restrict__ rows,
                                                     const int* __restrict__ cols,
                                                     const float* __restrict__ w,
                                                     int* __restrict__ bcnt,
                                                     int* __restrict__ tmpRow,
                                                     int2* __restrict__ tmpCW,
                                                     const float* __restrict__ X,
                                                     ushort* __restrict__ Xb,
                                                     const float* __restrict__ W1,
                                                     const float* __restrict__ W2,
                                                     ushort* __restrict__ W1T,
                                                     ushort* __restrict__ W2T,
                                                     uint32_t k0, uint32_t k1) {
    __shared__ int hist[NBUCK];
    __shared__ int base[NBUCK];
    if (blockIdx.x < SC_NBLK) {
        // ---- scatter path ----
        int e0 = blockIdx.x * EPB;
        for (int i = threadIdx.x; i < NBUCK; i += 256) hist[i] = 0;
        __syncthreads();
        int myrow[16];
#pragma unroll
        for (int k = 0; k < 16; ++k) {
            int e = e0 + k * 256 + threadIdx.x;
            int r = (e < N_EDGES) ? rows[e] : -1;
            if (r < 0 || r >= N_NODES) r = -1;   // defensive
            myrow[k] = r;
            if (r >= 0) atomicAdd(&hist[r >> BSH], 1);
        }
        __syncthreads();
        for (int b = threadIdx.x; b < NBUCK; b += 256) {
            int c = hist[b];
            base[b] = (c > 0) ? atomicAdd(&bcnt[b], c) : 0;
            hist[b] = 0;
        }
        __syncthreads();
#pragma unroll
        for (int k = 0; k < 16; ++k) {
            int r = myrow[k];
            if (r < 0) continue;
            int e = e0 + k * 256 + threadIdx.x;
            int b = r >> BSH;
            int pos = base[b] + atomicAdd(&hist[b], 1);
            if (pos < 0 || pos >= CAP) continue;   // defensive
            int slot = b * CAP + pos;
            tmpRow[slot] = r;
            tmpCW[slot] = make_int2(cols[e], __float_as_int(w[e]));
        }
    } else {
        // ---- dropout + weight-prep path ----
        int t = (blockIdx.x - SC_NBLK) * 256 + threadIdx.x;
        if (t < N_NODES * D / 4) {
            float4 v = ((const float4*)X)[t];
            uint32_t j = (uint32_t)t * 4u;
            float a = keep_mask(k0, k1, j + 0u) ? v.x * 2.f : 0.f;
            float b = keep_mask(k0, k1, j + 1u) ? v.y * 2.f : 0.f;
            float c = keep_mask(k0, k1, j + 2u) ? v.z * 2.f : 0.f;
            float d = keep_mask(k0, k1, j + 3u) ? v.w * 2.f : 0.f;
            uint2 o;
            o.x = f2bf(a) | (f2bf(b) << 16);
            o.y = f2bf(c) | (f2bf(d) << 16);
            ((uint2*)Xb)[t] = o;
        }
        if (t < 128 * 128 + 64 * 128) {
            if (t < 128 * 128) {
                int n = t >> 7, k = t & 127;
                W1T[n * 128 + k] = (ushort)f2bf(W1[k * 128 + n]);
            } else {
                int u = t - 128 * 128;
                int n = u >> 7, k = u & 127;
                W2T[n * 128 + k] = (ushort)f2bf(W2[k * 64 + n]);
            }
        }
    }
}

// per-bucket: local row counts + scan -> rowRange[], place edges -> epk (bucket-padded)
__global__ __launch_bounds__(256) void bucket_finalize(const int* __restrict__ bcnt,
                                                       const int* __restrict__ tmpRow,
                                                       const int2* __restrict__ tmpCW,
                                                       int2* __restrict__ rowRange,
                                                       int2* __restrict__ epk) {
    __shared__ int cnt[1 << BSH];
    __shared__ int scn[1 << BSH];
    __shared__ int cur[1 << BSH];
    int b = blockIdx.x;
    int r0 = b << BSH;
    int nr = N_NODES - r0;
    if (nr > (1 << BSH)) nr = 1 << BSH;
    int cb = bcnt[b];
    if (cb > CAP) cb = CAP;   // defensive
    int base = b * CAP;
    int tid = threadIdx.x;
    for (int i = tid; i < nr; i += 256) cnt[i] = 0;
    __syncthreads();
    for (int i = tid; i < cb; i += 256) {
        int r = tmpRow[base + i] - r0;
        if (r >= 0 && r < nr) atomicAdd(&cnt[r], 1);
    }
    __syncthreads();
    int myc = 0;
    if (tid < 128) {
        myc = (tid < nr) ? cnt[tid] : 0;
        scn[tid] = myc;
    }
    __syncthreads();
    for (int off = 1; off < 128; off <<= 1) {
        int v = 0;
        if (tid < 128 && tid >= off) v = scn[tid - off];
        __syncthreads();
        if (tid < 128 && tid >= off) scn[tid] += v;
        __syncthreads();
    }
    if (tid < nr) {
        int excl = scn[tid] - myc;
        rowRange[r0 + tid] = make_int2(base + excl, base + excl + myc);
        cur[tid] = base + excl;
    }
    __syncthreads();
    for (int i = tid; i < cb; i += 256) {
        int r = tmpRow[base + i] - r0;
        if (r < 0 || r >= nr) continue;
        int pos = atomicAdd(&cur[r], 1);
        if (pos < 0 || pos >= NBUCK * CAP) continue;   // defensive
        epk[pos] = tmpCW[base + i];
    }
}

// ---------------- SpMM 128-wide, bf16 gather -> bf16 out (8-deep MLP) ----------------
__global__ __launch_bounds__(256) void spmm128_bf16(const int2* __restrict__ rowRange,
                                                    const int2* __restrict__ epk,
                                                    const ushort* __restrict__ hb,
                                                    ushort* __restrict__ outb) {
    int t = blockIdx.x * blockDim.x + threadIdx.x;
    int r = t >> 4;
    if (r >= N_NODES) return;
    int lane = t & 15;
    int2 rr = rowRange[r];
    int s0 = rr.x, s1 = rr.y;
    float a0[8] = {0.f, 0.f, 0.f, 0.f, 0.f, 0.f, 0.f, 0.f};
    float a1[8] = {0.f, 0.f, 0.f, 0.f, 0.f, 0.f, 0.f, 0.f};
    int i = s0;
    for (; i + 8 <= s1; i += 8) {
        int2 e0 = epk[i],     e1 = epk[i + 1], e2 = epk[i + 2], e3 = epk[i + 3];
        int2 e4 = epk[i + 4], e5 = epk[i + 5], e6 = epk[i + 6], e7 = epk[i + 7];
        uint4 u0 = *(const uint4*)(hb + (size_t)e0.x * D + lane * 8);
        uint4 u1 = *(const uint4*)(hb + (size_t)e1.x * D + lane * 8);
        uint4 u2 = *(const uint4*)(hb + (size_t)e2.x * D + lane * 8);
        uint4 u3 = *(const uint4*)(hb + (size_t)e3.x * D + lane * 8);
        uint4 u4 = *(const uint4*)(hb + (size_t)e4.x * D + lane * 8);
        uint4 u5 = *(const uint4*)(hb + (size_t)e5.x * D + lane * 8);
        uint4 u6 = *(const uint4*)(hb + (size_t)e6.x * D + lane * 8);
        uint4 u7 = *(const uint4*)(hb + (size_t)e7.x * D + lane * 8);
        fma8(a0, u0, __int_as_float(e0.y));
        fma8(a1, u1, __int_as_float(e1.y));
        fma8(a0, u2, __int_as_float(e2.y));
        fma8(a1, u3, __int_as_float(e3.y));
        fma8(a0, u4, __int_as_float(e4.y));
        fma8(a1, u5, __int_as_float(e5.y));
        fma8(a0, u6, __int_as_float(e6.y));
        fma8(a1, u7, __int_as_float(e7.y));
    }
    for (; i + 4 <= s1; i += 4) {
        int2 e0 = epk[i], e1 = epk[i + 1], e2 = epk[i + 2], e3 = epk[i + 3];
        uint4 u0 = *(const uint4*)(hb + (size_t)e0.x * D + lane * 8);
        uint4 u1 = *(const uint4*)(hb + (size_t)e1.x * D + lane * 8);
        uint4 u2 = *(const uint4*)(hb + (size_t)e2.x * D + lane * 8);
        uint4 u3 = *(const uint4*)(hb + (size_t)e3.x * D + lane * 8);
        fma8(a0, u0, __int_as_float(e0.y));
        fma8(a1, u1, __int_as_float(e1.y));
        fma8(a0, u2, __int_as_float(e2.y));
        fma8(a1, u3, __int_as_float(e3.y));
    }
    for (; i < s1; ++i) {
        int2 e = epk[i];
        uint4 u = *(const uint4*)(hb + (size_t)e.x * D + lane * 8);
        fma8(a0, u, __int_as_float(e.y));
    }
    uint4 o;
    o.x = f2bf(a0[0] + a1[0]) | (f2bf(a0[1] + a1[1]) << 16);
    o.y = f2bf(a0[2] + a1[2]) | (f2bf(a0[3] + a1[3]) << 16);
    o.z = f2bf(a0[4] + a1[4]) | (f2bf(a0[5] + a1[5]) << 16);
    o.w = f2bf(a0[6] + a1[6]) | (f2bf(a0[7] + a1[7]) << 16);
    *(uint4*)(outb + (size_t)r * D + lane * 8) = o;
}

// ---------------- fused MFMA lin1+lin2 ----------------
#define LROW 136
__global__ __launch_bounds__(256) void lin12_mfma(const ushort* __restrict__ Bb,
                                                  const ushort* __restrict__ W1T,
                                                  const float* __restrict__ b1,
                                                  const ushort* __restrict__ W2T,
                                                  ushort* __restrict__ T,
                                                  uint32_t k0, uint32_t k1) {
    __shared__ ushort h1[4][16][LROW];
    int wave = threadIdx.x >> 6;
    int lane = threadIdx.x & 63;
    int lrow = lane & 15;
    int lhk  = lane >> 4;
    int rowBase = blockIdx.x * 64 + wave * 16;

    int arow = rowBase + lrow;
    if (arow >= N_NODES) arow = N_NODES - 1;
    const ushort* aptr = Bb + (size_t)arow * D + lhk * 8;
    bf16x8 afrag[4];
#pragma unroll
    for (int kb = 0; kb < 4; ++kb)
        afrag[kb] = *(const bf16x8*)(aptr + kb * 32);

    f32x4 acc[8];
#pragma unroll
    for (int nt = 0; nt < 8; ++nt) acc[nt] = (f32x4){0.f, 0.f, 0.f, 0.f};
#pragma unroll
    for (int nt = 0; nt < 8; ++nt) {
        const ushort* wp = W1T + (size_t)(nt * 16 + lrow) * 128 + lhk * 8;
#pragma unroll
        for (int kb = 0; kb < 4; ++kb) {
            bf16x8 bfrag = *(const bf16x8*)(wp + kb * 32);
            acc[nt] = __builtin_amdgcn_mfma_f32_16x16x32_bf16(afrag[kb], bfrag, acc[nt], 0, 0, 0);
        }
    }

#pragma unroll
    for (int nt = 0; nt < 8; ++nt) {
        int c = nt * 16 + lrow;
        float bias = b1[c];
#pragma unroll
        for (int v = 0; v < 4; ++v) {
            int rl = lhk * 4 + v;
            int row = rowBase + rl;
            float x = fmaxf(acc[nt][v] + bias, 0.f);
            uint32_t j = (uint32_t)row * 128u + (uint32_t)c;
            x = keep_mask(k0, k1, j) ? x * 2.f : 0.f;
            h1[wave][rl][c] = (ushort)f2bf(x);
        }
    }
    __syncthreads();

    bf16x8 a2[4];
#pragma unroll
    for (int kb = 0; kb < 4; ++kb)
        a2[kb] = *(const bf16x8*)&h1[wave][lrow][lhk * 8 + kb * 32];

    f32x4 acc2[4];
#pragma unroll
    for (int nt = 0; nt < 4; ++nt) acc2[nt] = (f32x4){0.f, 0.f, 0.f, 0.f};
#pragma unroll
    for (int nt = 0; nt < 4; ++nt) {
        const ushort* wp = W2T + (size_t)(nt * 16 + lrow) * 128 + lhk * 8;
#pragma unroll
        for (int kb = 0; kb < 4; ++kb) {
            bf16x8 bfrag = *(const bf16x8*)(wp + kb * 32);
            acc2[nt] = __builtin_amdgcn_mfma_f32_16x16x32_bf16(a2[kb], bfrag, acc2[nt], 0, 0, 0);
        }
    }

#pragma unroll
    for (int nt = 0; nt < 4; ++nt) {
        int c = nt * 16 + lrow;
#pragma unroll
        for (int v = 0; v < 4; ++v) {
            int row = rowBase + lhk * 4 + v;
            if (row < N_NODES)
                T[(size_t)row * DOUT + c] = (ushort)f2bf(acc2[nt][v]);
        }
    }
}

// ---------------- SpMM 64-wide + bias, bf16 gather -> fp32 out (8-deep MLP) ----------------
__global__ __launch_bounds__(256) void spmm64_bf16(const int2* __restrict__ rowRange,
                                                   const int2* __restrict__ epk,
                                                   const ushort* __restrict__ tb,
                                                   const float* __restrict__ b2,
                                                   float* __restrict__ out) {
    int t = blockIdx.x * blockDim.x + threadIdx.x;
    int r = t >> 3;
    if (r >= N_NODES) return;
    int lane = t & 7;
    int2 rr = rowRange[r];
    int s0 = rr.x, s1 = rr.y;
    float a0[8] = {0.f, 0.f, 0.f, 0.f, 0.f, 0.f, 0.f, 0.f};
    float a1[8] = {0.f, 0.f, 0.f, 0.f, 0.f, 0.f, 0.f, 0.f};
    int i = s0;
    for (; i + 8 <= s1; i += 8) {
        int2 e0 = epk[i],     e1 = epk[i + 1], e2 = epk[i + 2], e3 = epk[i + 3];
        int2 e4 = epk[i + 4], e5 = epk[i + 5], e6 = epk[i + 6], e7 = epk[i + 7];
        uint4 u0 = *(const uint4*)(tb + (size_t)e0.x * DOUT + lane * 8);
        uint4 u1 = *(const uint4*)(tb + (size_t)e1.x * DOUT + lane * 8);
        uint4 u2 = *(const uint4*)(tb + (size_t)e2.x * DOUT + lane * 8);
        uint4 u3 = *(const uint4*)(tb + (size_t)e3.x * DOUT + lane * 8);
        uint4 u4 = *(const uint4*)(tb + (size_t)e4.x * DOUT + lane * 8);
        uint4 u5 = *(const uint4*)(tb + (size_t)e5.x * DOUT + lane * 8);
        uint4 u6 = *(const uint4*)(tb + (size_t)e6.x * DOUT + lane * 8);
        uint4 u7 = *(const uint4*)(tb + (size_t)e7.x * DOUT + lane * 8);
        fma8(a0, u0, __int_as_float(e0.y));
        fma8(a1, u1, __int_as_float(e1.y));
        fma8(a0, u2, __int_as_float(e2.y));
        fma8(a1, u3, __int_as_float(e3.y));
        fma8(a0, u4, __int_as_float(e4.y));
        fma8(a1, u5, __int_as_float(e5.y));
        fma8(a0, u6, __int_as_float(e6.y));
        fma8(a1, u7, __int_as_float(e7.y));
    }
    for (; i + 4 <= s1; i += 4) {
        int2 e0 = epk[i], e1 = epk[i + 1], e2 = epk[i + 2], e3 = epk[i + 3];
        uint4 u0 = *(const uint4*)(tb + (size_t)e0.x * DOUT + lane * 8);
        uint4 u1 = *(const uint4*)(tb + (size_t)e1.x * DOUT + lane * 8);
        uint4 u2 = *(const uint4*)(tb + (size_t)e2.x * DOUT + lane * 8);
        uint4 u3 = *(const uint4*)(tb + (size_t)e3.x * DOUT + lane * 8);
        fma8(a0, u0, __int_as_float(e0.y));
        fma8(a1, u1, __int_as_float(e1.y));
        fma8(a0, u2, __int_as_float(e2.y));
        fma8(a1, u3, __int_as_float(e3.y));
    }
    for (; i < s1; ++i) {
        int2 e = epk[i];
        uint4 u = *(const uint4*)(tb + (size_t)e.x * DOUT + lane * 8);
        fma8(a0, u, __int_as_float(e.y));
    }
    float4 blo = *(const float4*)(b2 + lane * 8);
    float4 bhi = *(const float4*)(b2 + lane * 8 + 4);
    float* op = out + (size_t)r * DOUT + lane * 8;
    *(float4*)(op + 0) = make_float4(a0[0] + a1[0] + blo.x, a0[1] + a1[1] + blo.y,
                                     a0[2] + a1[2] + blo.z, a0[3] + a1[3] + blo.w);
    *(float4*)(op + 4) = make_float4(a0[4] + a1[4] + bhi.x, a0[5] + a1[5] + bhi.y,
                                     a0[6] + a1[6] + bhi.z, a0[7] + a1[7] + bhi.w);
}

extern "C" void kernel_launch(void* const* d_in, const int* in_sizes, int n_in,
                              void* d_out, int out_size, void* d_ws, size_t ws_size,
                              hipStream_t stream) {
    const int*   rows = (const int*)d_in[0];
    const int*   cols = (const int*)d_in[1];
    const float* w    = (const float*)d_in[2];
    const float* X    = (const float*)d_in[3];
    const float* W1   = (const float*)d_in[4];
    const float* b1   = (const float*)d_in[5];
    const float* W2   = (const float*)d_in[6];
    const float* b2   = (const float*)d_in[7];
    float* out = (float*)d_out;

    uint32_t ka0, ka1, kb0, kb1;
    threefry2x32(0u, 42u, 0u, 0u, ka0, ka1);  // k1 (drop1)
    threefry2x32(0u, 42u, 0u, 1u, kb0, kb1);  // k2 (drop2)

    // workspace layout
    char* p = (char*)d_ws;
    ushort* Xb        = (ushort*)p;            p += (size_t)N_NODES * D * 2;        // 12.8 MB
    ushort* Bb        = (ushort*)p;            p += (size_t)N_NODES * D * 2;        // 12.8 MB
    ushort* T         = (ushort*)p;            p += (size_t)N_NODES * DOUT * 2;     // 6.4 MB
    int2*   epk       = (int2*)p;              p += (size_t)NBUCK * CAP * 8;        // 8.0 MB
    int2*   tmpCW     = (int2*)p;              p += (size_t)NBUCK * CAP * 8;        // 8.0 MB
    int*    tmpRow    = (int*)p;               p += (size_t)NBUCK * CAP * 4;        // 4.0 MB
    int2*   rowRange  = (int2*)p;              p += (size_t)N_NODES * 8;            // 0.4 MB
    ushort* W1T       = (ushort*)p;            p += (size_t)128 * 128 * 2;
    ushort* W2T       = (ushort*)p;            p += (size_t)64 * 128 * 2;
    int*    bcnt      = (int*)p;               p += (size_t)NBUCK * 4;

    // ---- prologue ----
    hipMemsetAsync(bcnt, 0, (size_t)NBUCK * 4, stream);
    fusedA_kernel<<<SC_NBLK + DROP_NBLK, 256, 0, stream>>>(rows, cols, w, bcnt, tmpRow, tmpCW,
                                                           X, Xb, W1, W2, W1T, W2T, ka0, ka1);
    bucket_finalize<<<NBUCK, 256, 0, stream>>>(bcnt, tmpRow, tmpCW, rowRange, epk);

    // ---- forward ----
    spmm128_bf16<<<((size_t)N_NODES * 16 + 255) / 256, 256, 0, stream>>>(rowRange, epk, Xb, Bb);
    lin12_mfma<<<(N_NODES + 63) / 64, 256, 0, stream>>>(Bb, W1T, b1, W2T, T, kb0, kb1);
    spmm64_bf16<<<((size_t)N_NODES * 8 + 255) / 256, 256, 0, stream>>>(rowRange, epk, T, b2, out);
}

// Round 20
// 120.387 us; speedup vs baseline: 1.4283x; 1.0154x over previous
//
#include <hip/hip_runtime.h>
#include <stdint.h>

#define N_NODES 50000
#define N_EDGES 800000
#define D 128
#define DOUT 64

#define BSH 7                                  // rows per bucket = 128
#define NBUCK ((N_NODES + 127) >> BSH)         // 391
#define CAP 2560                               // slots per bucket
#define EPB 4096                               // edges per scatter block
#define SC_NBLK ((N_EDGES + EPB - 1) / EPB)    // 196
#define DROP_NBLK ((N_NODES * D / 4 + 255) / 256)  // 6250

typedef short bf16x8 __attribute__((ext_vector_type(8)));
typedef float f32x4 __attribute__((ext_vector_type(4)));

__host__ __device__ inline uint32_t rotl32(uint32_t v, int d) {
    return (v << d) | (v >> (32 - d));
}

// JAX threefry2x32 (20 rounds), matches jax/_src/prng.py
__host__ __device__ inline void threefry2x32(uint32_t k0, uint32_t k1,
                                             uint32_t x0, uint32_t x1,
                                             uint32_t& o0, uint32_t& o1) {
    uint32_t ks2 = 0x1BD11BDAu ^ k0 ^ k1;
    x0 += k0; x1 += k1;
#define TFR(d) { x0 += x1; x1 = rotl32(x1, d); x1 ^= x0; }
    TFR(13) TFR(15) TFR(26) TFR(6)
    x0 += k1;  x1 += ks2 + 1u;
    TFR(17) TFR(29) TFR(16) TFR(24)
    x0 += ks2; x1 += k0 + 2u;
    TFR(13) TFR(15) TFR(26) TFR(6)
    x0 += k0;  x1 += k1 + 3u;
    TFR(17) TFR(29) TFR(16) TFR(24)
    x0 += k1;  x1 += ks2 + 4u;
    TFR(13) TFR(15) TFR(26) TFR(6)
    x0 += ks2; x1 += k0 + 5u;
#undef TFR
    o0 = x0; o1 = x1;
}

// keep ⟺ u<0.5 ⟺ top bit of (b0^b1)==0
__device__ inline bool keep_mask(uint32_t k0, uint32_t k1, uint32_t j) {
    uint32_t b0, b1;
    threefry2x32(k0, k1, 0u, j, b0, b1);
    return ((int)(b0 ^ b1)) >= 0;
}

__device__ inline uint32_t f2bf(float f) {
    uint32_t u = __float_as_uint(f);
    return (u + 0x7fffu + ((u >> 16) & 1u)) >> 16;
}
__device__ inline float bf2f_lo(uint32_t u) { return __uint_as_float(u << 16); }
__device__ inline float bf2f_hi(uint32_t u) { return __uint_as_float(u & 0xffff0000u); }

__device__ inline void fma8(float* a, uint4 u, float w) {
    a[0] = fmaf(w, bf2f_lo(u.x), a[0]);
    a[1] = fmaf(w, bf2f_hi(u.x), a[1]);
    a[2] = fmaf(w, bf2f_lo(u.y), a[2]);
    a[3] = fmaf(w, bf2f_hi(u.y), a[3]);
    a[4] = fmaf(w, bf2f_lo(u.z), a[4]);
    a[5] = fmaf(w, bf2f_hi(u.z), a[5]);
    a[6] = fmaf(w, bf2f_lo(u.w), a[6]);
    a[7] = fmaf(w, bf2f_hi(u.w), a[7]);
}

// ---------------- fusedA: bucket scatter (blocks 0..195) | dropout+weights (rest) ----------------
__global__ __launch_bounds__(256) void fusedA_kernel(const int* __restrict__ rows,
                                                     const int* __restrict__ cols,
                                                     const float* __restrict__ w,
                                                     int* __restrict__ bcnt,
                                                     int* __restrict__ tmpRow,
                                                     int2* __restrict__ tmpCW,
                                                     const float* __restrict__ X,
                                                     ushort* __restrict__ Xb,
                                                     const float* __restrict__ W1,
                                                     const float* __restrict__ W2,
                                                     ushort* __restrict__ W1T,
                                                     ushort* __restrict__ W2T,
                                                     uint32_t k0, uint32_t k1) {
    __shared__ int hist[NBUCK];
    __shared__ int base[NBUCK];
    if (blockIdx.x < SC_NBLK) {
        // ---- scatter path ----
        int e0 = blockIdx.x * EPB;
        for (int i = threadIdx.x; i < NBUCK; i += 256) hist[i] = 0;
        __syncthreads();
        int myrow[16];
#pragma unroll
        for (int k = 0; k < 16; ++k) {
            int e = e0 + k * 256 + threadIdx.x;
            int r = (e < N_EDGES) ? rows[e] : -1;
            if (r < 0 || r >= N_NODES) r = -1;   // defensive
            myrow[k] = r;
            if (r >= 0) atomicAdd(&hist[r >> BSH], 1);
        }
        __syncthreads();
        for (int b = threadIdx.x; b < NBUCK; b += 256) {
            int c = hist[b];
            base[b] = (c > 0) ? atomicAdd(&bcnt[b], c) : 0;
            hist[b] = 0;
        }
        __syncthreads();
#pragma unroll
        for (int k = 0; k < 16; ++k) {
            int r = myrow[k];
            if (r < 0) continue;
            int e = e0 + k * 256 + threadIdx.x;
            int b = r >> BSH;
            int pos = base[b] + atomicAdd(&hist[b], 1);
            if (pos < 0 || pos >= CAP) continue;   // defensive
            int slot = b * CAP + pos;
            tmpRow[slot] = r;
            tmpCW[slot] = make_int2(cols[e], __float_as_int(w[e]));
        }
    } else {
        // ---- dropout + weight-prep path ----
        int t = (blockIdx.x - SC_NBLK) * 256 + threadIdx.x;
        if (t < N_NODES * D / 4) {
            float4 v = ((const float4*)X)[t];
            uint32_t j = (uint32_t)t * 4u;
            float a = keep_mask(k0, k1, j + 0u) ? v.x * 2.f : 0.f;
            float b = keep_mask(k0, k1, j + 1u) ? v.y * 2.f : 0.f;
            float c = keep_mask(k0, k1, j + 2u) ? v.z * 2.f : 0.f;
            float d = keep_mask(k0, k1, j + 3u) ? v.w * 2.f : 0.f;
            uint2 o;
            o.x = f2bf(a) | (f2bf(b) << 16);
            o.y = f2bf(c) | (f2bf(d) << 16);
            ((uint2*)Xb)[t] = o;
        }
        if (t < 128 * 128 + 64 * 128) {
            if (t < 128 * 128) {
                int n = t >> 7, k = t & 127;
                W1T[n * 128 + k] = (ushort)f2bf(W1[k * 128 + n]);
            } else {
                int u = t - 128 * 128;
                int n = u >> 7, k = u & 127;
                W2T[n * 128 + k] = (ushort)f2bf(W2[k * 64 + n]);
            }
        }
    }
}

// per-bucket: local row counts + scan -> rowRange[], place edges -> epk (bucket-padded)
__global__ __launch_bounds__(256) void bucket_finalize(const int* __restrict__ bcnt,
                                                       const int* __restrict__ tmpRow,
                                                       const int2* __restrict__ tmpCW,
                                                       int2* __restrict__ rowRange,
                                                       int2* __restrict__ epk) {
    __shared__ int cnt[1 << BSH];
    __shared__ int scn[1 << BSH];
    __shared__ int cur[1 << BSH];
    int b = blockIdx.x;
    int r0 = b << BSH;
    int nr = N_NODES - r0;
    if (nr > (1 << BSH)) nr = 1 << BSH;
    int cb = bcnt[b];
    if (cb > CAP) cb = CAP;   // defensive
    int base = b * CAP;
    int tid = threadIdx.x;
    for (int i = tid; i < nr; i += 256) cnt[i] = 0;
    __syncthreads();
    for (int i = tid; i < cb; i += 256) {
        int r = tmpRow[base + i] - r0;
        if (r >= 0 && r < nr) atomicAdd(&cnt[r], 1);
    }
    __syncthreads();
    int myc = 0;
    if (tid < 128) {
        myc = (tid < nr) ? cnt[tid] : 0;
        scn[tid] = myc;
    }
    __syncthreads();
    for (int off = 1; off < 128; off <<= 1) {
        int v = 0;
        if (tid < 128 && tid >= off) v = scn[tid - off];
        __syncthreads();
        if (tid < 128 && tid >= off) scn[tid] += v;
        __syncthreads();
    }
    if (tid < nr) {
        int excl = scn[tid] - myc;
        rowRange[r0 + tid] = make_int2(base + excl, base + excl + myc);
        cur[tid] = base + excl;
    }
    __syncthreads();
    for (int i = tid; i < cb; i += 256) {
        int r = tmpRow[base + i] - r0;
        if (r < 0 || r >= nr) continue;
        int pos = atomicAdd(&cur[r], 1);
        if (pos < 0 || pos >= NBUCK * CAP) continue;   // defensive
        epk[pos] = tmpCW[base + i];
    }
}

// ---------------- SpMM 128-wide, bf16 gather -> bf16 out (8-deep MLP) ----------------
__global__ __launch_bounds__(256) void spmm128_bf16(const int2* __restrict__ rowRange,
                                                    const int2* __restrict__ epk,
                                                    const ushort* __restrict__ hb,
                                                    ushort* __restrict__ outb) {
    int t = blockIdx.x * blockDim.x + threadIdx.x;
    int r = t >> 4;
    if (r >= N_NODES) return;
    int lane = t & 15;
    int2 rr = rowRange[r];
    int s0 = rr.x, s1 = rr.y;
    float a0[8] = {0.f, 0.f, 0.f, 0.f, 0.f, 0.f, 0.f, 0.f};
    float a1[8] = {0.f, 0.f, 0.f, 0.f, 0.f, 0.f, 0.f, 0.f};
    int i = s0;
    for (; i + 8 <= s1; i += 8) {
        int2 e0 = epk[i],     e1 = epk[i + 1], e2 = epk[i + 2], e3 = epk[i + 3];
        int2 e4 = epk[i + 4], e5 = epk[i + 5], e6 = epk[i + 6], e7 = epk[i + 7];
        uint4 u0 = *(const uint4*)(hb + (size_t)e0.x * D + lane * 8);
        uint4 u1 = *(const uint4*)(hb + (size_t)e1.x * D + lane * 8);
        uint4 u2 = *(const uint4*)(hb + (size_t)e2.x * D + lane * 8);
        uint4 u3 = *(const uint4*)(hb + (size_t)e3.x * D + lane * 8);
        uint4 u4 = *(const uint4*)(hb + (size_t)e4.x * D + lane * 8);
        uint4 u5 = *(const uint4*)(hb + (size_t)e5.x * D + lane * 8);
        uint4 u6 = *(const uint4*)(hb + (size_t)e6.x * D + lane * 8);
        uint4 u7 = *(const uint4*)(hb + (size_t)e7.x * D + lane * 8);
        fma8(a0, u0, __int_as_float(e0.y));
        fma8(a1, u1, __int_as_float(e1.y));
        fma8(a0, u2, __int_as_float(e2.y));
        fma8(a1, u3, __int_as_float(e3.y));
        fma8(a0, u4, __int_as_float(e4.y));
        fma8(a1, u5, __int_as_float(e5.y));
        fma8(a0, u6, __int_as_float(e6.y));
        fma8(a1, u7, __int_as_float(e7.y));
    }
    for (; i + 4 <= s1; i += 4) {
        int2 e0 = epk[i], e1 = epk[i + 1], e2 = epk[i + 2], e3 = epk[i + 3];
        uint4 u0 = *(const uint4*)(hb + (size_t)e0.x * D + lane * 8);
        uint4 u1 = *(const uint4*)(hb + (size_t)e1.x * D + lane * 8);
        uint4 u2 = *(const uint4*)(hb + (size_t)e2.x * D + lane * 8);
        uint4 u3 = *(const uint4*)(hb + (size_t)e3.x * D + lane * 8);
        fma8(a0, u0, __int_as_float(e0.y));
        fma8(a1, u1, __int_as_float(e1.y));
        fma8(a0, u2, __int_as_float(e2.y));
        fma8(a1, u3, __int_as_float(e3.y));
    }
    for (; i < s1; ++i) {
        int2 e = epk[i];
        uint4 u = *(const uint4*)(hb + (size_t)e.x * D + lane * 8);
        fma8(a0, u, __int_as_float(e.y));
    }
    uint4 o;
    o.x = f2bf(a0[0] + a1[0]) | (f2bf(a0[1] + a1[1]) << 16);
    o.y = f2bf(a0[2] + a1[2]) | (f2bf(a0[3] + a1[3]) << 16);
    o.z = f2bf(a0[4] + a1[4]) | (f2bf(a0[5] + a1[5]) << 16);
    o.w = f2bf(a0[6] + a1[6]) | (f2bf(a0[7] + a1[7]) << 16);
    *(uint4*)(outb + (size_t)r * D + lane * 8) = o;
}

// ---------------- fused MFMA lin1+lin2 — 1-wave blocks, barrier-free ----------------
// Each 64-thread block = one wave owning 16 rows; the hidden tile lives in its own
// 4.25 KB LDS slice; write->read is within-wave (lockstep + lgkmcnt), no barrier.
#define LROW 136
__global__ __launch_bounds__(64) void lin12_mfma(const ushort* __restrict__ Bb,
                                                 const ushort* __restrict__ W1T,
                                                 const float* __restrict__ b1,
                                                 const ushort* __restrict__ W2T,
                                                 ushort* __restrict__ T,
                                                 uint32_t k0, uint32_t k1) {
    __shared__ ushort h1[16][LROW];   // 4.25 KB
    int lane = threadIdx.x;           // 0..63
    int lrow = lane & 15;
    int lhk  = lane >> 4;
    int rowBase = blockIdx.x * 16;

    int arow = rowBase + lrow;
    if (arow >= N_NODES) arow = N_NODES - 1;
    const ushort* aptr = Bb + (size_t)arow * D + lhk * 8;
    bf16x8 afrag[4];
#pragma unroll
    for (int kb = 0; kb < 4; ++kb)
        afrag[kb] = *(const bf16x8*)(aptr + kb * 32);

    f32x4 acc[8];
#pragma unroll
    for (int nt = 0; nt < 8; ++nt) acc[nt] = (f32x4){0.f, 0.f, 0.f, 0.f};
#pragma unroll
    for (int nt = 0; nt < 8; ++nt) {
        const ushort* wp = W1T + (size_t)(nt * 16 + lrow) * 128 + lhk * 8;
#pragma unroll
        for (int kb = 0; kb < 4; ++kb) {
            bf16x8 bfrag = *(const bf16x8*)(wp + kb * 32);
            acc[nt] = __builtin_amdgcn_mfma_f32_16x16x32_bf16(afrag[kb], bfrag, acc[nt], 0, 0, 0);
        }
    }

    // epilogue1 -> hidden tile (within-wave write)
#pragma unroll
    for (int nt = 0; nt < 8; ++nt) {
        int c = nt * 16 + lrow;
        float bias = b1[c];
#pragma unroll
        for (int v = 0; v < 4; ++v) {
            int rl = lhk * 4 + v;
            int row = rowBase + rl;
            float x = fmaxf(acc[nt][v] + bias, 0.f);
            uint32_t j = (uint32_t)row * 128u + (uint32_t)c;
            x = keep_mask(k0, k1, j) ? x * 2.f : 0.f;
            h1[rl][c] = (ushort)f2bf(x);
        }
    }
    // no barrier: same-wave write->read, lockstep + lgkmcnt ordering

    bf16x8 a2[4];
#pragma unroll
    for (int kb = 0; kb < 4; ++kb)
        a2[kb] = *(const bf16x8*)&h1[lrow][lhk * 8 + kb * 32];

    f32x4 acc2[4];
#pragma unroll
    for (int nt = 0; nt < 4; ++nt) acc2[nt] = (f32x4){0.f, 0.f, 0.f, 0.f};
#pragma unroll
    for (int nt = 0; nt < 4; ++nt) {
        const ushort* wp = W2T + (size_t)(nt * 16 + lrow) * 128 + lhk * 8;
#pragma unroll
        for (int kb = 0; kb < 4; ++kb) {
            bf16x8 bfrag = *(const bf16x8*)(wp + kb * 32);
            acc2[nt] = __builtin_amdgcn_mfma_f32_16x16x32_bf16(a2[kb], bfrag, acc2[nt], 0, 0, 0);
        }
    }

#pragma unroll
    for (int nt = 0; nt < 4; ++nt) {
        int c = nt * 16 + lrow;
#pragma unroll
        for (int v = 0; v < 4; ++v) {
            int row = rowBase + lhk * 4 + v;
            if (row < N_NODES)
                T[(size_t)row * DOUT + c] = (ushort)f2bf(acc2[nt][v]);
        }
    }
}

// ---------------- SpMM 64-wide + bias, bf16 gather -> fp32 out (8-deep MLP) ----------------
__global__ __launch_bounds__(256) void spmm64_bf16(const int2* __restrict__ rowRange,
                                                   const int2* __restrict__ epk,
                                                   const ushort* __restrict__ tb,
                                                   const float* __restrict__ b2,
                                                   float* __restrict__ out) {
    int t = blockIdx.x * blockDim.x + threadIdx.x;
    int r = t >> 3;
    if (r >= N_NODES) return;
    int lane = t & 7;
    int2 rr = rowRange[r];
    int s0 = rr.x, s1 = rr.y;
    float a0[8] = {0.f, 0.f, 0.f, 0.f, 0.f, 0.f, 0.f, 0.f};
    float a1[8] = {0.f, 0.f, 0.f, 0.f, 0.f, 0.f, 0.f, 0.f};
    int i = s0;
    for (; i + 8 <= s1; i += 8) {
        int2 e0 = epk[i],     e1 = epk[i + 1], e2 = epk[i + 2], e3 = epk[i + 3];
        int2 e4 = epk[i + 4], e5 = epk[i + 5], e6 = epk[i + 6], e7 = epk[i + 7];
        uint4 u0 = *(const uint4*)(tb + (size_t)e0.x * DOUT + lane * 8);
        uint4 u1 = *(const uint4*)(tb + (size_t)e1.x * DOUT + lane * 8);
        uint4 u2 = *(const uint4*)(tb + (size_t)e2.x * DOUT + lane * 8);
        uint4 u3 = *(const uint4*)(tb + (size_t)e3.x * DOUT + lane * 8);
        uint4 u4 = *(const uint4*)(tb + (size_t)e4.x * DOUT + lane * 8);
        uint4 u5 = *(const uint4*)(tb + (size_t)e5.x * DOUT + lane * 8);
        uint4 u6 = *(const uint4*)(tb + (size_t)e6.x * DOUT + lane * 8);
        uint4 u7 = *(const uint4*)(tb + (size_t)e7.x * DOUT + lane * 8);
        fma8(a0, u0, __int_as_float(e0.y));
        fma8(a1, u1, __int_as_float(e1.y));
        fma8(a0, u2, __int_as_float(e2.y));
        fma8(a1, u3, __int_as_float(e3.y));
        fma8(a0, u4, __int_as_float(e4.y));
        fma8(a1, u5, __int_as_float(e5.y));
        fma8(a0, u6, __int_as_float(e6.y));
        fma8(a1, u7, __int_as_float(e7.y));
    }
    for (; i + 4 <= s1; i += 4) {
        int2 e0 = epk[i], e1 = epk[i + 1], e2 = epk[i + 2], e3 = epk[i + 3];
        uint4 u0 = *(const uint4*)(tb + (size_t)e0.x * DOUT + lane * 8);
        uint4 u1 = *(const uint4*)(tb + (size_t)e1.x * DOUT + lane * 8);
        uint4 u2 = *(const uint4*)(tb + (size_t)e2.x * DOUT + lane * 8);
        uint4 u3 = *(const uint4*)(tb + (size_t)e3.x * DOUT + lane * 8);
        fma8(a0, u0, __int_as_float(e0.y));
        fma8(a1, u1, __int_as_float(e1.y));
        fma8(a0, u2, __int_as_float(e2.y));
        fma8(a1, u3, __int_as_float(e3.y));
    }
    for (; i < s1; ++i) {
        int2 e = epk[i];
        uint4 u = *(const uint4*)(tb + (size_t)e.x * DOUT + lane * 8);
        fma8(a0, u, __int_as_float(e.y));
    }
    float4 blo = *(const float4*)(b2 + lane * 8);
    float4 bhi = *(const float4*)(b2 + lane * 8 + 4);
    float* op = out + (size_t)r * DOUT + lane * 8;
    *(float4*)(op + 0) = make_float4(a0[0] + a1[0] + blo.x, a0[1] + a1[1] + blo.y,
                                     a0[2] + a1[2] + blo.z, a0[3] + a1[3] + blo.w);
    *(float4*)(op + 4) = make_float4(a0[4] + a1[4] + bhi.x, a0[5] + a1[5] + bhi.y,
                                     a0[6] + a1[6] + bhi.z, a0[7] + a1[7] + bhi.w);
}

extern "C" void kernel_launch(void* const* d_in, const int* in_sizes, int n_in,
                              void* d_out, int out_size, void* d_ws, size_t ws_size,
                              hipStream_t stream) {
    const int*   rows = (const int*)d_in[0];
    const int*   cols = (const int*)d_in[1];
    const float* w    = (const float*)d_in[2];
    const float* X    = (const float*)d_in[3];
    const float* W1   = (const float*)d_in[4];
    const float* b1   = (const float*)d_in[5];
    const float* W2   = (const float*)d_in[6];
    const float* b2   = (const float*)d_in[7];
    float* out = (float*)d_out;

    uint32_t ka0, ka1, kb0, kb1;
    threefry2x32(0u, 42u, 0u, 0u, ka0, ka1);  // k1 (drop1)
    threefry2x32(0u, 42u, 0u, 1u, kb0, kb1);  // k2 (drop2)

    // workspace layout
    char* p = (char*)d_ws;
    ushort* Xb        = (ushort*)p;            p += (size_t)N_NODES * D * 2;        // 12.8 MB
    ushort* Bb        = (ushort*)p;            p += (size_t)N_NODES * D * 2;        // 12.8 MB
    ushort* T         = (ushort*)p;            p += (size_t)N_NODES * DOUT * 2;     // 6.4 MB
    int2*   epk       = (int2*)p;              p += (size_t)NBUCK * CAP * 8;        // 8.0 MB
    int2*   tmpCW     = (int2*)p;              p += (size_t)NBUCK * CAP * 8;        // 8.0 MB
    int*    tmpRow    = (int*)p;               p += (size_t)NBUCK * CAP * 4;        // 4.0 MB
    int2*   rowRange  = (int2*)p;              p += (size_t)N_NODES * 8;            // 0.4 MB
    ushort* W1T       = (ushort*)p;            p += (size_t)128 * 128 * 2;
    ushort* W2T       = (ushort*)p;            p += (size_t)64 * 128 * 2;
    int*    bcnt      = (int*)p;               p += (size_t)NBUCK * 4;

    // ---- prologue ----
    hipMemsetAsync(bcnt, 0, (size_t)NBUCK * 4, stream);
    fusedA_kernel<<<SC_NBLK + DROP_NBLK, 256, 0, stream>>>(rows, cols, w, bcnt, tmpRow, tmpCW,
                                                           X, Xb, W1, W2, W1T, W2T, ka0, ka1);
    bucket_finalize<<<NBUCK, 256, 0, stream>>>(bcnt, tmpRow, tmpCW, rowRange, epk);

    // ---- forward ----
    spmm128_bf16<<<((size_t)N_NODES * 16 + 255) / 256, 256, 0, stream>>>(rowRange, epk, Xb, Bb);
    lin12_mfma<<<(N_NODES + 15) / 16, 64, 0, stream>>>(Bb, W1T, b1, W2T, T, kb0, kb1);
    spmm64_bf16<<<((size_t)N_NODES * 8 + 255) / 256, 256, 0, stream>>>(rowRange, epk, T, b2, out);
}